// Round 14
// baseline (523.293 us; speedup 1.0000x reference)
//
#include <hip/hip_runtime.h>
#include <hip/hip_bf16.h>

#define NN 100000
#define NE 800000
#define NBLK 391  // ceil(NN/256)

typedef unsigned short u16;
typedef unsigned int u32;
typedef __attribute__((ext_vector_type(8))) short short8v;
typedef __attribute__((ext_vector_type(4))) float f32x4;

// wf offsets
enum {
  W1E = 0, B1 = 144, W2 = 160, B2 = 4768, W3 = 4800, B3 = 9408, W4 = 9424,
  B4 = 9568, WL0 = 9600, WR0 = 10624, BS0 = 11648, WL1 = 11776, WR1 = 28160,
  BS1 = 44544, WL2 = 44672, WR2 = 61056, BS2 = 77440, WL3 = 77568, WR3 = 77696,
  BS3 = 77824
};

__device__ __forceinline__ float us2f(u16 u) {
  union { u32 i; float f; } c; c.i = ((u32)u) << 16; return c.f;
}
__device__ __forceinline__ u16 f2us(float f) {
  union { __hip_bfloat16 h; u16 u; } c; c.h = __float2bfloat16(f); return c.u;
}
__device__ __forceinline__ u32 pk2(float a, float b) {
  return (u32)f2us(a) | ((u32)f2us(b) << 16);
}
__device__ __forceinline__ float ldin(const void* p, long i, int isbf) {
  return isbf ? us2f(((const u16*)p)[i]) : ((const float*)p)[i];
}

// ---------- dtype detection ----------
__global__ void detect_k(const void* x, int* flag) {
  if (threadIdx.x == 0) {
    const u16* u = (const u16*)x;
    int good = 0;
    for (int i = 0; i < 256; ++i) {
      int e = (u[2 * i] >> 7) & 0xFF;
      if (e >= 64 && e <= 141) ++good;
    }
    *flag = (good >= 200) ? 1 : 0;
  }
}

// ---------- weight conversion ----------
struct Jobs {
  const void* p[19];
  int off[19];
  int n[19];
};
__global__ void cvt_all_k(Jobs jb, float* __restrict__ wf, const int* __restrict__ flag) {
  int j = blockIdx.y;
  int i = blockIdx.x * 256 + threadIdx.x;
  int isbf = *flag;
  if (i < jb.n[j]) wf[jb.off[j] + i] = ldin(jb.p[j], i, isbf);
}

__global__ void w1eff_k(const void* __restrict__ w1, float* __restrict__ wf,
                        const int* __restrict__ flag) {
  int i = threadIdx.x;
  int isbf = *flag;
  if (i < 144) {
    int oc = i / 9, k = i - oc * 9;
    float s = 0.f;
#pragma unroll
    for (int ic = 0; ic < 6; ++ic) s += ldin(w1, (oc * 6 + ic) * 9 + k, isbf);
    wf[i] = s;
  }
}

__global__ void wcat_k(const float* __restrict__ wf, u16* __restrict__ WT1,
                       u16* __restrict__ WT2) {
  int i = blockIdx.x * 256 + threadIdx.x;
  if (i < 32768) {
    int n = i >> 8, k = i & 255;
    WT1[i] = f2us(wf[(k < 128 ? WR1 : WL1) + (k & 127) * 128 + n]);
    WT2[i] = f2us(wf[(k < 128 ? WR2 : WL2) + (k & 127) * 128 + n]);
  }
}

// WT3[tap][oc=16][ic=32] bf16 for conv3 MFMA B-fragments
__global__ void wcat3_k(const float* __restrict__ wf, u16* __restrict__ WT3) {
  int i = blockIdx.x * 256 + threadIdx.x;
  if (i < 4608) {
    int tap = i >> 9;
    int rem = i & 511;
    int oc = rem >> 5, ic = rem & 31;
    WT3[i] = f2us(wf[W3 + oc * 288 + ic * 9 + tap]);
  }
}

// WT2M[(pair*2+half)*16+oc][k32]
__global__ void wcat2m_k(const float* __restrict__ wf, u16* __restrict__ W) {
  int i = blockIdx.x * 256 + threadIdx.x;
  if (i < 5120) {
    int k = i & 31;
    int oc = (i >> 5) & 15;
    int h = (i >> 9) & 1;
    int p = i >> 10;
    int tap = p * 2 + (k >> 4);
    int ic = k & 15;
    float v = (tap <= 8) ? wf[W2 + (h * 16 + oc) * 144 + ic * 9 + tap] : 0.f;
    W[i] = f2us(v);
  }
}

// ---------- conv1: 1->16 ch, 1 px/thread; bf16 out (NHWC or planar) ----------
template <bool NHWC>
__global__ __launch_bounds__(256) void conv1_k(const void* __restrict__ x128,
                                               const float* __restrict__ wf,
                                               u16* __restrict__ h1,
                                               const int* __restrict__ flag, int img0) {
  __shared__ float s_in[324];
  __shared__ float s_w[160];
  int bx = blockIdx.x;
  int n = bx >> 6;
  int ty0 = ((bx >> 3) & 7) << 4, tx0 = (bx & 7) << 4;
  int tid = threadIdx.x;
  int isbf = *flag;
  if (tid < 160) s_w[tid] = wf[tid];
  for (int i = tid; i < 324; i += 256) {
    int py = i / 18, px = i - py * 18;
    int gy = ty0 + py - 1, gx = tx0 + px - 1;
    float v = 0.f;
    if (gy >= 0 && gy < 128 && gx >= 0 && gx < 128)
      v = ldin(x128, ((long)(img0 + n) << 14) + (gy << 7) + gx, isbf);
    s_in[i] = v;
  }
  __syncthreads();
  int ty = tid >> 4, tx = tid & 15;
  const float* bi = &s_in[ty * 18 + tx];
  float a0 = bi[0], a1 = bi[1], a2 = bi[2], a3 = bi[18], a4 = bi[19], a5 = bi[20],
        a6 = bi[36], a7 = bi[37], a8 = bi[38];
  int opix = ((ty0 + ty) << 7) + (tx0 + tx);
  float rv[16];
#pragma unroll
  for (int oc = 0; oc < 16; ++oc) {
    const float* w = s_w + oc * 9;
    float acc = s_w[144 + oc] + a0 * w[0] + a1 * w[1] + a2 * w[2] + a3 * w[3] +
                a4 * w[4] + a5 * w[5] + a6 * w[6] + a7 * w[7] + a8 * w[8];
    rv[oc] = fmaxf(acc, 0.f);
  }
  if (NHWC) {
    long base = (((long)(img0 + n) << 14) + opix) * 16;
    uint4 w0, w1;
    w0.x = pk2(rv[0], rv[1]);   w0.y = pk2(rv[2], rv[3]);
    w0.z = pk2(rv[4], rv[5]);   w0.w = pk2(rv[6], rv[7]);
    w1.x = pk2(rv[8], rv[9]);   w1.y = pk2(rv[10], rv[11]);
    w1.z = pk2(rv[12], rv[13]); w1.w = pk2(rv[14], rv[15]);
    *(uint4*)&h1[base] = w0;
    *(uint4*)&h1[base + 8] = w1;
  } else {
#pragma unroll
    for (int oc = 0; oc < 16; ++oc)
      h1[((long)(n * 16 + oc) << 14) + opix] = f2us(rv[oc]);
  }
}

// ---------- conv2 (big path): paired-tap MFMA implicit GEMM, NHWC->NHWC ----------
__global__ __launch_bounds__(256) void conv2m_k(const u16* __restrict__ h1t,
                                                const u16* __restrict__ WT2M,
                                                const float* __restrict__ wf,
                                                u16* __restrict__ h2t) {
  int bx = blockIdx.x;
  int img = bx >> 6;
  int t = bx & 63;
  int ty0 = (t >> 3) << 4, tx0 = (t & 7) << 4;
  int tid = threadIdx.x;
  int wave = tid >> 6, lane = tid & 63;
  int l15 = lane & 15, lk = lane >> 4;
  long ibase = (long)img << 14;
  short8v B[5][2];
#pragma unroll
  for (int p = 0; p < 5; ++p)
#pragma unroll
    for (int h = 0; h < 2; ++h)
      B[p][h] = *(const short8v*)&WT2M[(((p * 2 + h) << 4) + l15) * 32 + lk * 8];
  float bias0 = wf[B2 + l15];
  float bias1 = wf[B2 + 16 + l15];
#pragma unroll 1
  for (int rg = 0; rg < 4; ++rg) {
    int y = ty0 + wave * 4 + rg;
    f32x4 acc0 = {}, acc1 = {};
#pragma unroll
    for (int p = 0; p < 5; ++p) {
      int tap = min(p * 2 + (lk >> 1), 8);
      int dy = tap / 3 - 1, dx = tap % 3 - 1;
      int yy = y + dy, xx = tx0 + l15 + dx;
      short8v a = {};
      if (yy >= 0 && yy < 128 && xx >= 0 && xx < 128)
        a = *(const short8v*)&h1t[(ibase + (yy << 7) + xx) * 16 + (lk & 1) * 8];
      acc0 = __builtin_amdgcn_mfma_f32_16x16x32_bf16(a, B[p][0], acc0, 0, 0, 0);
      acc1 = __builtin_amdgcn_mfma_f32_16x16x32_bf16(a, B[p][1], acc1, 0, 0, 0);
    }
#pragma unroll
    for (int q = 0; q < 4; ++q) {
      int px = tx0 + lk * 4 + q;
      long o = (ibase + (y << 7) + px) * 32;
      h2t[o + l15] = f2us(fmaxf(acc0[q] + bias0, 0.f));
      h2t[o + 16 + l15] = f2us(fmaxf(acc1[q] + bias1, 0.f));
    }
  }
}

// ---------- conv2 (small path): round-7 VALU version, planar ----------
__global__ __launch_bounds__(256) void conv2_k(const u16* __restrict__ h1c,
                                               const float* __restrict__ wf,
                                               u16* __restrict__ out) {
  __shared__ float s_in[8 * 18 * 35];
  int bx = blockIdx.x;
  int n = bx >> 5;
  int rem = bx & 31;
  int y0 = (rem >> 2) << 4;
  int x0 = (rem & 3) << 5;
  int tid = threadIdx.x;
  int ocb = __builtin_amdgcn_readfirstlane((tid >> 7) << 4);
  int r = (tid >> 3) & 15;
  int c4 = (tid & 7) << 2;
  float acc[16][4];
#pragma unroll
  for (int o = 0; o < 16; ++o)
#pragma unroll
    for (int p = 0; p < 4; ++p) acc[o][p] = 0.f;
#pragma unroll 1
  for (int pass = 0; pass < 2; ++pass) {
    __syncthreads();
    for (int i = tid; i < 4896; i += 256) {
      int icl = i / 612;
      int p = i - icl * 612;
      int py = p / 34, px = p - py * 34;
      int gy = y0 + py - 1, gx = x0 + px - 1;
      float v = 0.f;
      if (gy >= 0 && gy < 128 && gx >= 0 && gx < 128)
        v = us2f(h1c[((long)(n * 16 + pass * 8 + icl) << 14) + (gy << 7) + gx]);
      s_in[(icl * 18 + py) * 35 + px] = v;
    }
    __syncthreads();
#pragma unroll 1
    for (int icl = 0; icl < 8; ++icl) {
      int ic = pass * 8 + icl;
      float a[3][6];
#pragma unroll
      for (int dy = 0; dy < 3; ++dy)
#pragma unroll
        for (int dx = 0; dx < 6; ++dx)
          a[dy][dx] = s_in[(icl * 18 + r + dy) * 35 + c4 + dx];
      const float* wb = wf + W2 + ic * 9;
#pragma unroll
      for (int o = 0; o < 16; ++o) {
        const float* wo = wb + (ocb + o) * 144;
        float w0 = wo[0], w1 = wo[1], w2 = wo[2], w3 = wo[3], w4 = wo[4],
              w5 = wo[5], w6 = wo[6], w7 = wo[7], w8 = wo[8];
#pragma unroll
        for (int p = 0; p < 4; ++p)
          acc[o][p] += a[0][p] * w0 + a[0][p + 1] * w1 + a[0][p + 2] * w2 +
                       a[1][p] * w3 + a[1][p + 1] * w4 + a[1][p + 2] * w5 +
                       a[2][p] * w6 + a[2][p + 1] * w7 + a[2][p + 2] * w8;
      }
    }
  }
  int opix = ((y0 + r) << 7) + x0 + c4;
#pragma unroll
  for (int o = 0; o < 16; ++o) {
    float b = wf[B2 + ocb + o];
    ushort4 v;
    v.x = f2us(fmaxf(acc[o][0] + b, 0.f));
    v.y = f2us(fmaxf(acc[o][1] + b, 0.f));
    v.z = f2us(fmaxf(acc[o][2] + b, 0.f));
    v.w = f2us(fmaxf(acc[o][3] + b, 0.f));
    *(ushort4*)&out[((long)(n * 32 + ocb + o) << 14) + opix] = v;
  }
}

// ---------- conv3 (big path): 9-tap MFMA implicit GEMM, NHWC ----------
__global__ __launch_bounds__(256) void conv3m_k(const u16* __restrict__ h2t,
                                                const u16* __restrict__ WT3,
                                                const float* __restrict__ wf,
                                                u16* __restrict__ h3t) {
  int bx = blockIdx.x;
  int img = bx >> 6;
  int t = bx & 63;
  int ty0 = (t >> 3) << 4, tx0 = (t & 7) << 4;
  int tid = threadIdx.x;
  int wave = tid >> 6, lane = tid & 63;
  int l15 = lane & 15, lk = lane >> 4;
  long ibase = (long)img << 14;
  short8v B[9];
#pragma unroll
  for (int tap = 0; tap < 9; ++tap)
    B[tap] = *(const short8v*)&WT3[tap * 512 + l15 * 32 + lk * 8];
  float bias = wf[B3 + l15];
#pragma unroll 1
  for (int rg = 0; rg < 4; ++rg) {
    int y = ty0 + wave * 4 + rg;
    f32x4 acc = {};
#pragma unroll
    for (int tap = 0; tap < 9; ++tap) {
      int dy = tap / 3 - 1, dx = tap % 3 - 1;
      int yy = y + dy, xx = tx0 + l15 + dx;
      short8v a = {};
      if (yy >= 0 && yy < 128 && xx >= 0 && xx < 128)
        a = *(const short8v*)&h2t[(ibase + (yy << 7) + xx) * 32 + lk * 8];
      acc = __builtin_amdgcn_mfma_f32_16x16x32_bf16(a, B[tap], acc, 0, 0, 0);
    }
#pragma unroll
    for (int q = 0; q < 4; ++q) {
      int px = tx0 + lk * 4 + q;
      h3t[(ibase + (y << 7) + px) * 16 + l15] = f2us(fmaxf(acc[q] + bias, 0.f));
    }
  }
}

// ---------- conv3 (small path): round-10 VALU version, planar ----------
__global__ __launch_bounds__(256) void conv3_k(const u16* __restrict__ h2c,
                                               const float* __restrict__ wf,
                                               u16* __restrict__ h3c) {
  __shared__ float s_in[8 * 18 * 35];
  int bx = blockIdx.x;
  int n = bx >> 5;
  int rem = bx & 31;
  int y0 = (rem >> 2) << 4;
  int x0 = (rem & 3) << 5;
  int tid = threadIdx.x;
  int r = tid >> 4;
  int c2 = (tid & 15) << 1;
  float acc[16][2];
#pragma unroll
  for (int o = 0; o < 16; ++o) { acc[o][0] = 0.f; acc[o][1] = 0.f; }
#pragma unroll 1
  for (int pass = 0; pass < 4; ++pass) {
    __syncthreads();
    for (int i = tid; i < 4896; i += 256) {
      int icl = i / 612;
      int p = i - icl * 612;
      int py = p / 34, px = p - py * 34;
      int gy = y0 + py - 1, gx = x0 + px - 1;
      float v = 0.f;
      if (gy >= 0 && gy < 128 && gx >= 0 && gx < 128)
        v = us2f(h2c[((long)(n * 32 + pass * 8 + icl) << 14) + (gy << 7) + gx]);
      s_in[(icl * 18 + py) * 35 + px] = v;
    }
    __syncthreads();
#pragma unroll 1
    for (int icl = 0; icl < 8; ++icl) {
      int ic = pass * 8 + icl;
      float a[3][4];
#pragma unroll
      for (int dy = 0; dy < 3; ++dy)
#pragma unroll
        for (int dx = 0; dx < 4; ++dx)
          a[dy][dx] = s_in[(icl * 18 + r + dy) * 35 + c2 + dx];
#pragma unroll
      for (int o = 0; o < 16; ++o) {
        const float* wo = wf + W3 + o * 288 + ic * 9;
        float w0 = wo[0], w1 = wo[1], w2 = wo[2], w3 = wo[3], w4 = wo[4],
              w5 = wo[5], w6 = wo[6], w7 = wo[7], w8 = wo[8];
#pragma unroll
        for (int p = 0; p < 2; ++p)
          acc[o][p] += a[0][p] * w0 + a[0][p + 1] * w1 + a[0][p + 2] * w2 +
                       a[1][p] * w3 + a[1][p + 1] * w4 + a[1][p + 2] * w5 +
                       a[2][p] * w6 + a[2][p + 1] * w7 + a[2][p + 2] * w8;
      }
    }
  }
  int opix = ((y0 + r) << 7) + x0 + c2;
#pragma unroll
  for (int o = 0; o < 16; ++o) {
    float b = wf[B3 + o];
    u32 v = pk2(fmaxf(acc[o][0] + b, 0.f), fmaxf(acc[o][1] + b, 0.f));
    *(u32*)&h3c[((long)(n * 16 + o) << 14) + opix] = v;
  }
}

// ---------- conv4 (big path): NHWC direct, 1 px/thread, no LDS ----------
__global__ __launch_bounds__(256) void conv4n_k(const u16* __restrict__ h3t,
                                                const float* __restrict__ wf,
                                                float* __restrict__ x1f,
                                                void* __restrict__ out0,
                                                const int* __restrict__ flag) {
  int pix = blockIdx.x * 256 + threadIdx.x;
  int loc = pix & 16383;
  int y = loc >> 7, x = loc & 127;
  float acc = wf[B4];
#pragma unroll
  for (int tap = 0; tap < 9; ++tap) {
    int dy = tap / 3 - 1, dx = tap % 3 - 1;
    int yy = y + dy, xx = x + dx;
    if (yy >= 0 && yy < 128 && xx >= 0 && xx < 128) {
      const u16* v = &h3t[((long)pix + (dy << 7) + dx) * 16];
      uint4 a = *(const uint4*)v;
      uint4 b = *(const uint4*)(v + 8);
      u32 vv[8] = {a.x, a.y, a.z, a.w, b.x, b.y, b.z, b.w};
      float s = 0.f;
#pragma unroll
      for (int h = 0; h < 8; ++h) {
        s += us2f((u16)(vv[h] & 0xFFFF)) * wf[W4 + (2 * h) * 9 + tap];
        s += us2f((u16)(vv[h] >> 16)) * wf[W4 + (2 * h + 1) * 9 + tap];
      }
      acc += s;
    }
  }
  x1f[pix] = acc;
  if (*flag) ((u16*)out0)[pix] = f2us(acc);
  else ((float*)out0)[pix] = acc;
}

// ---------- conv4 (small path): planar, LDS version ----------
__global__ __launch_bounds__(256) void conv4_k(const u16* __restrict__ h3c,
                                               const float* __restrict__ wf,
                                               float* __restrict__ x1f,
                                               void* __restrict__ out0,
                                               const int* __restrict__ flag, int img0) {
  __shared__ float s_in[16 * 324];
  int bx = blockIdx.x;
  int n = bx >> 6;
  int ty0 = ((bx >> 3) & 7) << 4, tx0 = (bx & 7) << 4;
  int tid = threadIdx.x;
  for (int i = tid; i < 16 * 324; i += 256) {
    int ic = i / 324, p = i - ic * 324;
    int py = p / 18, px = p - py * 18;
    int gy = ty0 + py - 1, gx = tx0 + px - 1;
    float v = 0.f;
    if (gy >= 0 && gy < 128 && gx >= 0 && gx < 128)
      v = us2f(h3c[((long)(n * 16 + ic) << 14) + (gy << 7) + gx]);
    s_in[i] = v;
  }
  __syncthreads();
  int ty = tid >> 4, tx = tid & 15;
  float acc = wf[B4];
#pragma unroll 1
  for (int ic = 0; ic < 16; ++ic) {
    const float* bi = &s_in[ic * 324 + ty * 18 + tx];
    const float* w = wf + W4 + ic * 9;
    acc += bi[0] * w[0] + bi[1] * w[1] + bi[2] * w[2] + bi[18] * w[3] + bi[19] * w[4] +
           bi[20] * w[5] + bi[36] * w[6] + bi[37] * w[7] + bi[38] * w[8];
  }
  int idx = ((img0 + n) << 14) + ((ty0 + ty) << 7) + (tx0 + tx);
  x1f[idx] = acc;
  if (*flag) ((u16*)out0)[idx] = f2us(acc);
  else ((float*)out0)[idx] = acc;
}

// ---------- graph node features ----------
__global__ void gather_h0_k(const void* __restrict__ pos, const void* __restrict__ xn,
                            const int* __restrict__ batch, const float* __restrict__ x1f,
                            float* __restrict__ h0, const int* __restrict__ flag) {
  int n = blockIdx.x * 256 + threadIdx.x;
  if (n >= NN) return;
  int isbf = *flag;
  float px = ldin(pos, 2 * n, isbf), py = ldin(pos, 2 * n + 1, isbf);
  int ix = (int)rintf((px / 20.0f) * 127.0f);
  int iy = (int)rintf((py / 20.0f) * 127.0f);
  ix = min(max(ix, 0), 127);
  iy = min(max(iy, 0), 127);
  float cn = x1f[(batch[n] << 14) + (iy << 7) + ix];
  float* o = h0 + n * 8;
#pragma unroll
  for (int k = 0; k < 5; ++k) o[k] = ldin(xn, n * 5 + k, isbf);
  o[5] = px;
  o[6] = py;
  o[7] = cn;
}

// ---------- CSR build ----------
__global__ void deg_k(const int* __restrict__ dst, int* __restrict__ deg) {
  int e = blockIdx.x * 256 + threadIdx.x;
  if (e < NE) atomicAdd(&deg[dst[e]], 1);
}
__global__ void scanA_k(const int* __restrict__ deg, int* __restrict__ bsum) {
  __shared__ int s[256];
  int i = blockIdx.x * 256 + threadIdx.x;
  s[threadIdx.x] = (i < NN) ? deg[i] : 0;
  __syncthreads();
  for (int o = 128; o; o >>= 1) {
    if (threadIdx.x < o) s[threadIdx.x] += s[threadIdx.x + o];
    __syncthreads();
  }
  if (threadIdx.x == 0) bsum[blockIdx.x] = s[0];
}
__global__ __launch_bounds__(512) void scanB_k(const int* __restrict__ bsum,
                                               int* __restrict__ bpre) {
  __shared__ int s[512];
  int t = threadIdx.x;
  int v = (t < NBLK) ? bsum[t] : 0;
  s[t] = v;
  __syncthreads();
  for (int o = 1; o < 512; o <<= 1) {
    int u = (t >= o) ? s[t - o] : 0;
    __syncthreads();
    s[t] += u;
    __syncthreads();
  }
  if (t < NBLK) bpre[t] = s[t] - v;
}
__global__ void scanC_k(const int* __restrict__ deg, const int* __restrict__ bpre,
                        int* __restrict__ off, int* __restrict__ curs,
                        float* __restrict__ invd) {
  __shared__ int s[256];
  int i = blockIdx.x * 256 + threadIdx.x, t = threadIdx.x;
  int v = (i < NN) ? deg[i] : 0;
  s[t] = v;
  __syncthreads();
  for (int o = 1; o < 256; o <<= 1) {
    int u = (t >= o) ? s[t - o] : 0;
    __syncthreads();
    s[t] += u;
    __syncthreads();
  }
  if (i < NN) {
    int e = bpre[blockIdx.x] + s[t] - v;
    off[i] = e;
    curs[i] = e;
    invd[i] = 1.0f / fmaxf((float)v, 1.0f);
  }
  if (i == 0) off[NN] = NE;
}
__global__ void fill_k(const int* __restrict__ src, const int* __restrict__ dst,
                       int* __restrict__ curs, int* __restrict__ ss) {
  int e = blockIdx.x * 256 + threadIdx.x;
  if (e < NE) ss[atomicAdd(&curs[dst[e]], 1)] = src[e];
}

// ---------- SAGE layer 0 ----------
__global__ void agg8_k(const float* __restrict__ h0, const int* __restrict__ off,
                       const int* __restrict__ ss, const float* __restrict__ invd,
                       float* __restrict__ m8) {
  int gid = blockIdx.x * 256 + threadIdx.x;
  if (gid >= NN * 8) return;
  int n = gid >> 3, f = gid & 7;
  int e0 = off[n], e1 = off[n + 1];
  float s = 0.f;
  for (int j = e0; j < e1; ++j) s += h0[ss[j] * 8 + f];
  m8[gid] = s * invd[n];
}
__global__ void combine0_k(const float* __restrict__ h0, const float* __restrict__ m8,
                           const float* __restrict__ wl, const float* __restrict__ wr,
                           const float* __restrict__ bs, u16* __restrict__ OUT) {
  int gid = blockIdx.x * 256 + threadIdx.x;
  int n = gid >> 7, fo = gid & 127;
  float acc = bs[fo];
#pragma unroll
  for (int fi = 0; fi < 8; ++fi)
    acc += m8[n * 8 + fi] * wl[fi * 128 + fo] + h0[n * 8 + fi] * wr[fi * 128 + fo];
  OUT[gid] = f2us(fmaxf(acc, 0.f));
}

// ---------- SAGE 128->128: fused gather-mean + MFMA; 32 nodes/block ----------
// phase 1: 8 edge-lanes x 4 f-lanes (32 feats each); prefetched offsets+indices
__global__ __launch_bounds__(256) void sage_mfma_k(
    const u16* __restrict__ X, const int* __restrict__ off, const int* __restrict__ ss,
    const float* __restrict__ invd, const u16* __restrict__ WT,
    const float* __restrict__ bs, u16* __restrict__ OUT) {
  __shared__ __align__(16) u16 sM[32 * 128];  // 8 KB
  int tid = threadIdx.x;
  int nodeBase = blockIdx.x * 32;
  {
    int grp = tid >> 5, t = tid & 31;
    int elane = t >> 2;   // 0..7 edge lanes
    int fl = t & 3;       // 0..3 feature blocks of 32
    int fbase = fl << 5;
    int e0s[4], e1s[4], sidx[4];
#pragma unroll
    for (int rep = 0; rep < 4; ++rep) {
      int node = nodeBase + grp * 4 + rep;
      e0s[rep] = off[node];
      e1s[rep] = off[node + 1];
    }
#pragma unroll
    for (int rep = 0; rep < 4; ++rep) {
      int j = e0s[rep] + elane;
      sidx[rep] = (j < e1s[rep]) ? ss[j] : -1;
    }
#pragma unroll 1
    for (int rep = 0; rep < 4; ++rep) {
      int nl = grp * 4 + rep;
      int node = nodeBase + nl;
      float s[32];
#pragma unroll
      for (int k = 0; k < 32; ++k) s[k] = 0.f;
      if (sidx[rep] >= 0) {
        const u16* row = &X[(long)sidx[rep] * 128 + fbase];
        uint4 q0 = *(const uint4*)row;
        uint4 q1 = *(const uint4*)(row + 8);
        uint4 q2 = *(const uint4*)(row + 16);
        uint4 q3 = *(const uint4*)(row + 24);
        u32 w[16] = {q0.x, q0.y, q0.z, q0.w, q1.x, q1.y, q1.z, q1.w,
                     q2.x, q2.y, q2.z, q2.w, q3.x, q3.y, q3.z, q3.w};
#pragma unroll
        for (int h = 0; h < 16; ++h) {
          s[2 * h] += us2f((u16)(w[h] & 0xFFFF));
          s[2 * h + 1] += us2f((u16)(w[h] >> 16));
        }
      }
      for (int j = e0s[rep] + elane + 8; j < e1s[rep]; j += 8) {
        const u16* row = &X[(long)ss[j] * 128 + fbase];
        uint4 q0 = *(const uint4*)row;
        uint4 q1 = *(const uint4*)(row + 8);
        uint4 q2 = *(const uint4*)(row + 16);
        uint4 q3 = *(const uint4*)(row + 24);
        u32 w[16] = {q0.x, q0.y, q0.z, q0.w, q1.x, q1.y, q1.z, q1.w,
                     q2.x, q2.y, q2.z, q2.w, q3.x, q3.y, q3.z, q3.w};
#pragma unroll
        for (int h = 0; h < 16; ++h) {
          s[2 * h] += us2f((u16)(w[h] & 0xFFFF));
          s[2 * h + 1] += us2f((u16)(w[h] >> 16));
        }
      }
#pragma unroll
      for (int k = 0; k < 32; ++k) {
        s[k] += __shfl_xor(s[k], 4);
        s[k] += __shfl_xor(s[k], 8);
        s[k] += __shfl_xor(s[k], 16);
      }
      if (elane == 0) {
        float iv = invd[node];
        int swz = (nl & 7) << 3;
#pragma unroll
        for (int c = 0; c < 4; ++c) {
          int b = c * 8;
          uint4 wv;
          wv.x = pk2(s[b] * iv, s[b + 1] * iv);
          wv.y = pk2(s[b + 2] * iv, s[b + 3] * iv);
          wv.z = pk2(s[b + 4] * iv, s[b + 5] * iv);
          wv.w = pk2(s[b + 6] * iv, s[b + 7] * iv);
          *(uint4*)&sM[nl * 128 + ((fbase + b) ^ swz)] = wv;
        }
      }
    }
  }
  __syncthreads();
  int wave = tid >> 6, lane = tid & 63;
  if (wave >= 2) return;
  int l15 = lane & 15, lk = lane >> 4;
  int arow = nodeBase + wave * 16 + l15;
  int mrow = wave * 16 + l15;
  f32x4 acc[8] = {};
#pragma unroll 1
  for (int ks = 0; ks < 8; ++ks) {
    short8v a;
    if (ks < 4) {
      a = *(const short8v*)&X[arow * 128 + ks * 32 + lk * 8];
    } else {
      int koff = (ks - 4) * 32 + lk * 8;
      a = *(const short8v*)&sM[mrow * 128 + (koff ^ ((mrow & 7) << 3))];
    }
#pragma unroll
    for (int r = 0; r < 8; ++r) {
      short8v b = *(const short8v*)&WT[(r * 16 + l15) * 256 + ks * 32 + lk * 8];
      acc[r] = __builtin_amdgcn_mfma_f32_16x16x32_bf16(a, b, acc[r], 0, 0, 0);
    }
  }
#pragma unroll
  for (int r = 0; r < 8; ++r) {
    int n = r * 16 + l15;
    float bias = bs[n];
#pragma unroll
    for (int q = 0; q < 4; ++q) {
      int node = nodeBase + wave * 16 + lk * 4 + q;
      OUT[node * 128 + n] = f2us(fmaxf(acc[r][q] + bias, 0.f));
    }
  }
}

// ---------- last layer ----------
__global__ __launch_bounds__(256) void dots_k(const u16* __restrict__ X,
                                              const float* __restrict__ wl,
                                              const float* __restrict__ wr,
                                              float* __restrict__ YL,
                                              float* __restrict__ YR) {
  __shared__ float swl[128], swr[128];
  int tid = threadIdx.x;
  if (tid < 128) swl[tid] = wl[tid];
  else swr[tid - 128] = wr[tid - 128];
  __syncthreads();
  int g = blockIdx.x * 8 + (tid >> 5);
  int t = tid & 31, f0 = t * 4;
  if (g >= NN) return;
  ushort4 r = *(const ushort4*)&X[g * 128 + f0];
  float x0 = us2f(r.x), x1 = us2f(r.y), x2 = us2f(r.z), x3 = us2f(r.w);
  float pl = x0 * swl[f0] + x1 * swl[f0 + 1] + x2 * swl[f0 + 2] + x3 * swl[f0 + 3];
  float pr = x0 * swr[f0] + x1 * swr[f0 + 1] + x2 * swr[f0 + 2] + x3 * swr[f0 + 3];
#pragma unroll
  for (int o = 16; o; o >>= 1) {
    pl += __shfl_xor(pl, o);
    pr += __shfl_xor(pr, o);
  }
  if (t == 0) {
    YL[g] = pl;
    YR[g] = pr;
  }
}

__global__ void last_k(const float* __restrict__ YL, const float* __restrict__ YR,
                       const int* __restrict__ off, const int* __restrict__ ss,
                       const float* __restrict__ invd, const float* __restrict__ bs,
                       void* __restrict__ gout, const int* __restrict__ flag) {
  int n = blockIdx.x * 256 + threadIdx.x;
  if (n >= NN) return;
  int e0 = off[n], e1 = off[n + 1];
  float s0 = 0.f, s1 = 0.f;
  int j = e0;
  for (; j + 1 < e1; j += 2) {
    s0 += YL[ss[j]];
    s1 += YL[ss[j + 1]];
  }
  if (j < e1) s0 += YL[ss[j]];
  float v = YR[n] + (s0 + s1) * invd[n] + bs[0];
  if (*flag) ((u16*)gout)[1048576 + n] = f2us(v);
  else ((float*)gout)[1048576 + n] = v;
}

// ---------- diagnostic ----------
__global__ void diag_k(u16* out, int n, u16 v) {
  int i = blockIdx.x * 256 + threadIdx.x;
  if (i < n) out[i] = v;
}

extern "C" void kernel_launch(void* const* d_in, const int* in_sizes, int n_in,
                              void* d_out, int out_size, void* d_ws, size_t ws_size,
                              hipStream_t stream) {
  const void* x128 = d_in[0];
  const void* xn = d_in[1];
  const void* pos = d_in[2];
  const int* eidx = (const int*)d_in[3];
  const int* batch = (const int*)d_in[4];
  const int* esrc = eidx;
  const int* edst = eidx + NE;

  const size_t REQUIRED = 66910000;
  const size_t REQUIRED_BIG = 210640000;
  if (ws_size < REQUIRED) {
    union { float f; u32 i; } c;
    c.f = (float)(ws_size >> 20);
    diag_k<<<(out_size + 255) / 256, 256, 0, stream>>>((u16*)d_out, out_size,
                                                       (u16)(c.i >> 16));
    return;
  }
  const bool big = (ws_size >= REQUIRED_BIG);

  char* ws = (char*)d_ws;
  float* x1f = (float*)ws;
  u16* WT1 = (u16*)(ws + 0);
  u16* WT2 = (u16*)(ws + 65536);
  float* YL = (float*)(ws + 131072);
  float* YR = (float*)(ws + 531072);
  u16* h1c = (u16*)(ws + 4194304);
  u16* h2c = big ? (u16*)(ws + 71303168) : (u16*)(ws + 20971520);
  u16* h3c = h1c;
  u16* WT3 = (u16*)(ws + 138412032);
  u16* WT2M = (u16*)(ws + 138421248);
  float* h0 = (float*)(ws + 4194304);
  float* m8 = (float*)(ws + 7394304);
  u16* HA = (u16*)(ws + 10594304);
  u16* HB = (u16*)(ws + 36194304);
  size_t base = big ? 205520896UL : 61794304UL;
  float* wf = (float*)(ws + base);
  int* deg = (int*)(ws + base + 312320);
  float* invd = (float*)(ws + base + 712320);
  int* noff = (int*)(ws + base + 1112320);
  int* curs = (int*)(ws + base + 1512576);
  int* ssrc = (int*)(ws + base + 1912576);
  int* bsum = (int*)(ws + base + 5112576);
  int* bpre = (int*)(ws + base + 5114368);
  int* flag = (int*)(ws + base + 5116160);

  detect_k<<<1, 64, 0, stream>>>(x128, flag);

  Jobs jb;
  const int jin[19] = {6, 7, 8, 9, 10, 11, 12, 13, 14, 15, 16, 17, 18, 19, 20, 21, 22, 23, 24};
  const int joff[19] = {B1, W2, B2, W3, B3, W4, B4, WL0, WR0, BS0, WL1, WR1, BS1,
                        WL2, WR2, BS2, WL3, WR3, BS3};
  const int jn[19] = {16, 4608, 32, 4608, 16, 144, 1, 1024, 1024, 128, 16384, 16384,
                      128, 16384, 16384, 128, 128, 128, 1};
  for (int j = 0; j < 19; ++j) { jb.p[j] = d_in[jin[j]]; jb.off[j] = joff[j]; jb.n[j] = jn[j]; }
  cvt_all_k<<<dim3(64, 19), 256, 0, stream>>>(jb, wf, flag);
  w1eff_k<<<1, 256, 0, stream>>>(d_in[5], wf, flag);

  if (big) {
    wcat3_k<<<18, 256, 0, stream>>>(wf, WT3);
    wcat2m_k<<<20, 256, 0, stream>>>(wf, WT2M);
    conv1_k<true><<<4096, 256, 0, stream>>>(x128, wf, h1c, flag, 0);
    conv2m_k<<<4096, 256, 0, stream>>>(h1c, WT2M, wf, h2c);
    conv3m_k<<<4096, 256, 0, stream>>>(h2c, WT3, wf, h3c);
    conv4n_k<<<4096, 256, 0, stream>>>(h3c, wf, x1f, d_out, flag);
  } else {
    for (int c = 0; c < 4; ++c) {
      int img0 = c * 16;
      conv1_k<false><<<1024, 256, 0, stream>>>(x128, wf, h1c, flag, img0);
      conv2_k<<<512, 256, 0, stream>>>(h1c, wf, h2c);
      conv3_k<<<512, 256, 0, stream>>>(h2c, wf, h3c);
      conv4_k<<<1024, 256, 0, stream>>>(h3c, wf, x1f, d_out, flag, img0);
    }
  }

  gather_h0_k<<<(NN + 255) / 256, 256, 0, stream>>>(pos, xn, batch, x1f, h0, flag);
  wcat_k<<<128, 256, 0, stream>>>(wf, WT1, WT2);

  hipMemsetAsync(deg, 0, NN * sizeof(int), stream);
  deg_k<<<(NE + 255) / 256, 256, 0, stream>>>(edst, deg);
  scanA_k<<<NBLK, 256, 0, stream>>>(deg, bsum);
  scanB_k<<<1, 512, 0, stream>>>(bsum, bpre);
  scanC_k<<<NBLK, 256, 0, stream>>>(deg, bpre, noff, curs, invd);
  fill_k<<<(NE + 255) / 256, 256, 0, stream>>>(esrc, edst, curs, ssrc);

  agg8_k<<<(NN * 8 + 255) / 256, 256, 0, stream>>>(h0, noff, ssrc, invd, m8);
  combine0_k<<<NN * 128 / 256, 256, 0, stream>>>(h0, m8, wf + WL0, wf + WR0, wf + BS0, HA);
  sage_mfma_k<<<3125, 256, 0, stream>>>(HA, noff, ssrc, invd, WT1, wf + BS1, HB);
  sage_mfma_k<<<3125, 256, 0, stream>>>(HB, noff, ssrc, invd, WT2, wf + BS2, HA);
  dots_k<<<12500, 256, 0, stream>>>(HA, wf + WL3, wf + WR3, YL, YR);
  last_k<<<(NN + 255) / 256, 256, 0, stream>>>(YL, YR, noff, ssrc, invd, wf + BS3,
                                               d_out, flag);
}

// Round 16
// 487.995 us; speedup vs baseline: 1.0723x; 1.0723x over previous
//
#include <hip/hip_runtime.h>
#include <hip/hip_bf16.h>

#define NN 100000
#define NE 800000
#define NBLK 391  // ceil(NN/256)

typedef unsigned short u16;
typedef unsigned int u32;
typedef __attribute__((ext_vector_type(8))) short short8v;
typedef __attribute__((ext_vector_type(4))) float f32x4;

// wf offsets
enum {
  W1E = 0, B1 = 144, W2 = 160, B2 = 4768, W3 = 4800, B3 = 9408, W4 = 9424,
  B4 = 9568, WL0 = 9600, WR0 = 10624, BS0 = 11648, WL1 = 11776, WR1 = 28160,
  BS1 = 44544, WL2 = 44672, WR2 = 61056, BS2 = 77440, WL3 = 77568, WR3 = 77696,
  BS3 = 77824
};

__device__ __forceinline__ float us2f(u16 u) {
  union { u32 i; float f; } c; c.i = ((u32)u) << 16; return c.f;
}
__device__ __forceinline__ u16 f2us(float f) {
  union { __hip_bfloat16 h; u16 u; } c; c.h = __float2bfloat16(f); return c.u;
}
__device__ __forceinline__ u32 pk2(float a, float b) {
  return (u32)f2us(a) | ((u32)f2us(b) << 16);
}
__device__ __forceinline__ float ldin(const void* p, long i, int isbf) {
  return isbf ? us2f(((const u16*)p)[i]) : ((const float*)p)[i];
}

// ---------- dtype detection ----------
__global__ void detect_k(const void* x, int* flag) {
  if (threadIdx.x == 0) {
    const u16* u = (const u16*)x;
    int good = 0;
    for (int i = 0; i < 256; ++i) {
      int e = (u[2 * i] >> 7) & 0xFF;
      if (e >= 64 && e <= 141) ++good;
    }
    *flag = (good >= 200) ? 1 : 0;
  }
}

// ---------- weight conversion ----------
struct Jobs {
  const void* p[19];
  int off[19];
  int n[19];
};
__global__ void cvt_all_k(Jobs jb, float* __restrict__ wf, const int* __restrict__ flag) {
  int j = blockIdx.y;
  int i = blockIdx.x * 256 + threadIdx.x;
  int isbf = *flag;
  if (i < jb.n[j]) wf[jb.off[j] + i] = ldin(jb.p[j], i, isbf);
}

__global__ void w1eff_k(const void* __restrict__ w1, float* __restrict__ wf,
                        const int* __restrict__ flag) {
  int i = threadIdx.x;
  int isbf = *flag;
  if (i < 144) {
    int oc = i / 9, k = i - oc * 9;
    float s = 0.f;
#pragma unroll
    for (int ic = 0; ic < 6; ++ic) s += ldin(w1, (oc * 6 + ic) * 9 + k, isbf);
    wf[i] = s;
  }
}

// WT1/WT2: launched AFTER gather_h0 (x1f region dead by then!)
__global__ void wcat_k(const float* __restrict__ wf, u16* __restrict__ WT1,
                       u16* __restrict__ WT2) {
  int i = blockIdx.x * 256 + threadIdx.x;
  if (i < 32768) {
    int n = i >> 8, k = i & 255;
    WT1[i] = f2us(wf[(k < 128 ? WR1 : WL1) + (k & 127) * 128 + n]);
    WT2[i] = f2us(wf[(k < 128 ? WR2 : WL2) + (k & 127) * 128 + n]);
  }
}

// WT3[tap][oc=16][ic=32] (big-path buffer region only)
__global__ void wcat3_k(const float* __restrict__ wf, u16* __restrict__ WT3) {
  int i = blockIdx.x * 256 + threadIdx.x;
  if (i < 4608) {
    int tap = i >> 9;
    int rem = i & 511;
    int oc = rem >> 5, ic = rem & 31;
    WT3[i] = f2us(wf[W3 + oc * 288 + ic * 9 + tap]);
  }
}

// WT2M[(pair*2+half)*16+oc][k32]
__global__ void wcat2m_k(const float* __restrict__ wf, u16* __restrict__ W) {
  int i = blockIdx.x * 256 + threadIdx.x;
  if (i < 5120) {
    int k = i & 31;
    int oc = (i >> 5) & 15;
    int h = (i >> 9) & 1;
    int p = i >> 10;
    int tap = p * 2 + (k >> 4);
    int ic = k & 15;
    float v = (tap <= 8) ? wf[W2 + (h * 16 + oc) * 144 + ic * 9 + tap] : 0.f;
    W[i] = f2us(v);
  }
}

// ---------- conv1: 1->16 ch, 1 px/thread; bf16 out (NHWC or planar) ----------
template <bool NHWC>
__global__ __launch_bounds__(256) void conv1_k(const void* __restrict__ x128,
                                               const float* __restrict__ wf,
                                               u16* __restrict__ h1,
                                               const int* __restrict__ flag, int img0) {
  __shared__ float s_in[324];
  __shared__ float s_w[160];
  int bx = blockIdx.x;
  int n = bx >> 6;
  int ty0 = ((bx >> 3) & 7) << 4, tx0 = (bx & 7) << 4;
  int tid = threadIdx.x;
  int isbf = *flag;
  if (tid < 160) s_w[tid] = wf[tid];
  for (int i = tid; i < 324; i += 256) {
    int py = i / 18, px = i - py * 18;
    int gy = ty0 + py - 1, gx = tx0 + px - 1;
    float v = 0.f;
    if (gy >= 0 && gy < 128 && gx >= 0 && gx < 128)
      v = ldin(x128, ((long)(img0 + n) << 14) + (gy << 7) + gx, isbf);
    s_in[i] = v;
  }
  __syncthreads();
  int ty = tid >> 4, tx = tid & 15;
  const float* bi = &s_in[ty * 18 + tx];
  float a0 = bi[0], a1 = bi[1], a2 = bi[2], a3 = bi[18], a4 = bi[19], a5 = bi[20],
        a6 = bi[36], a7 = bi[37], a8 = bi[38];
  int opix = ((ty0 + ty) << 7) + (tx0 + tx);
  float rv[16];
#pragma unroll
  for (int oc = 0; oc < 16; ++oc) {
    const float* w = s_w + oc * 9;
    float acc = s_w[144 + oc] + a0 * w[0] + a1 * w[1] + a2 * w[2] + a3 * w[3] +
                a4 * w[4] + a5 * w[5] + a6 * w[6] + a7 * w[7] + a8 * w[8];
    rv[oc] = fmaxf(acc, 0.f);
  }
  if (NHWC) {
    long base = (((long)(img0 + n) << 14) + opix) * 16;
    uint4 w0, w1;
    w0.x = pk2(rv[0], rv[1]);   w0.y = pk2(rv[2], rv[3]);
    w0.z = pk2(rv[4], rv[5]);   w0.w = pk2(rv[6], rv[7]);
    w1.x = pk2(rv[8], rv[9]);   w1.y = pk2(rv[10], rv[11]);
    w1.z = pk2(rv[12], rv[13]); w1.w = pk2(rv[14], rv[15]);
    *(uint4*)&h1[base] = w0;
    *(uint4*)&h1[base + 8] = w1;
  } else {
#pragma unroll
    for (int oc = 0; oc < 16; ++oc)
      h1[((long)(n * 16 + oc) << 14) + opix] = f2us(rv[oc]);
  }
}

// ---------- conv2 (big path): paired-tap MFMA implicit GEMM, NHWC->NHWC ----------
__global__ __launch_bounds__(256) void conv2m_k(const u16* __restrict__ h1t,
                                                const u16* __restrict__ WT2M,
                                                const float* __restrict__ wf,
                                                u16* __restrict__ h2t) {
  int bx = blockIdx.x;
  int img = bx >> 6;
  int t = bx & 63;
  int ty0 = (t >> 3) << 4, tx0 = (t & 7) << 4;
  int tid = threadIdx.x;
  int wave = tid >> 6, lane = tid & 63;
  int l15 = lane & 15, lk = lane >> 4;
  long ibase = (long)img << 14;
  short8v B[5][2];
#pragma unroll
  for (int p = 0; p < 5; ++p)
#pragma unroll
    for (int h = 0; h < 2; ++h)
      B[p][h] = *(const short8v*)&WT2M[(((p * 2 + h) << 4) + l15) * 32 + lk * 8];
  float bias0 = wf[B2 + l15];
  float bias1 = wf[B2 + 16 + l15];
#pragma unroll 1
  for (int rg = 0; rg < 4; ++rg) {
    int y = ty0 + wave * 4 + rg;
    f32x4 acc0 = {}, acc1 = {};
#pragma unroll
    for (int p = 0; p < 5; ++p) {
      int tap = min(p * 2 + (lk >> 1), 8);
      int dy = tap / 3 - 1, dx = tap % 3 - 1;
      int yy = y + dy, xx = tx0 + l15 + dx;
      short8v a = {};
      if (yy >= 0 && yy < 128 && xx >= 0 && xx < 128)
        a = *(const short8v*)&h1t[(ibase + (yy << 7) + xx) * 16 + (lk & 1) * 8];
      acc0 = __builtin_amdgcn_mfma_f32_16x16x32_bf16(a, B[p][0], acc0, 0, 0, 0);
      acc1 = __builtin_amdgcn_mfma_f32_16x16x32_bf16(a, B[p][1], acc1, 0, 0, 0);
    }
#pragma unroll
    for (int q = 0; q < 4; ++q) {
      int px = tx0 + lk * 4 + q;
      long o = (ibase + (y << 7) + px) * 32;
      h2t[o + l15] = f2us(fmaxf(acc0[q] + bias0, 0.f));
      h2t[o + 16 + l15] = f2us(fmaxf(acc1[q] + bias1, 0.f));
    }
  }
}

// ---------- conv2 (small path): round-7 VALU version, planar ----------
__global__ __launch_bounds__(256) void conv2_k(const u16* __restrict__ h1c,
                                               const float* __restrict__ wf,
                                               u16* __restrict__ out) {
  __shared__ float s_in[8 * 18 * 35];
  int bx = blockIdx.x;
  int n = bx >> 5;
  int rem = bx & 31;
  int y0 = (rem >> 2) << 4;
  int x0 = (rem & 3) << 5;
  int tid = threadIdx.x;
  int ocb = __builtin_amdgcn_readfirstlane((tid >> 7) << 4);
  int r = (tid >> 3) & 15;
  int c4 = (tid & 7) << 2;
  float acc[16][4];
#pragma unroll
  for (int o = 0; o < 16; ++o)
#pragma unroll
    for (int p = 0; p < 4; ++p) acc[o][p] = 0.f;
#pragma unroll 1
  for (int pass = 0; pass < 2; ++pass) {
    __syncthreads();
    for (int i = tid; i < 4896; i += 256) {
      int icl = i / 612;
      int p = i - icl * 612;
      int py = p / 34, px = p - py * 34;
      int gy = y0 + py - 1, gx = x0 + px - 1;
      float v = 0.f;
      if (gy >= 0 && gy < 128 && gx >= 0 && gx < 128)
        v = us2f(h1c[((long)(n * 16 + pass * 8 + icl) << 14) + (gy << 7) + gx]);
      s_in[(icl * 18 + py) * 35 + px] = v;
    }
    __syncthreads();
#pragma unroll 1
    for (int icl = 0; icl < 8; ++icl) {
      int ic = pass * 8 + icl;
      float a[3][6];
#pragma unroll
      for (int dy = 0; dy < 3; ++dy)
#pragma unroll
        for (int dx = 0; dx < 6; ++dx)
          a[dy][dx] = s_in[(icl * 18 + r + dy) * 35 + c4 + dx];
      const float* wb = wf + W2 + ic * 9;
#pragma unroll
      for (int o = 0; o < 16; ++o) {
        const float* wo = wb + (ocb + o) * 144;
        float w0 = wo[0], w1 = wo[1], w2 = wo[2], w3 = wo[3], w4 = wo[4],
              w5 = wo[5], w6 = wo[6], w7 = wo[7], w8 = wo[8];
#pragma unroll
        for (int p = 0; p < 4; ++p)
          acc[o][p] += a[0][p] * w0 + a[0][p + 1] * w1 + a[0][p + 2] * w2 +
                       a[1][p] * w3 + a[1][p + 1] * w4 + a[1][p + 2] * w5 +
                       a[2][p] * w6 + a[2][p + 1] * w7 + a[2][p + 2] * w8;
      }
    }
  }
  int opix = ((y0 + r) << 7) + x0 + c4;
#pragma unroll
  for (int o = 0; o < 16; ++o) {
    float b = wf[B2 + ocb + o];
    ushort4 v;
    v.x = f2us(fmaxf(acc[o][0] + b, 0.f));
    v.y = f2us(fmaxf(acc[o][1] + b, 0.f));
    v.z = f2us(fmaxf(acc[o][2] + b, 0.f));
    v.w = f2us(fmaxf(acc[o][3] + b, 0.f));
    *(ushort4*)&out[((long)(n * 32 + ocb + o) << 14) + opix] = v;
  }
}

// ---------- conv3 (big path): 9-tap MFMA implicit GEMM, NHWC ----------
__global__ __launch_bounds__(256) void conv3m_k(const u16* __restrict__ h2t,
                                                const u16* __restrict__ WT3,
                                                const float* __restrict__ wf,
                                                u16* __restrict__ h3t) {
  int bx = blockIdx.x;
  int img = bx >> 6;
  int t = bx & 63;
  int ty0 = (t >> 3) << 4, tx0 = (t & 7) << 4;
  int tid = threadIdx.x;
  int wave = tid >> 6, lane = tid & 63;
  int l15 = lane & 15, lk = lane >> 4;
  long ibase = (long)img << 14;
  short8v B[9];
#pragma unroll
  for (int tap = 0; tap < 9; ++tap)
    B[tap] = *(const short8v*)&WT3[tap * 512 + l15 * 32 + lk * 8];
  float bias = wf[B3 + l15];
#pragma unroll 1
  for (int rg = 0; rg < 4; ++rg) {
    int y = ty0 + wave * 4 + rg;
    f32x4 acc = {};
#pragma unroll
    for (int tap = 0; tap < 9; ++tap) {
      int dy = tap / 3 - 1, dx = tap % 3 - 1;
      int yy = y + dy, xx = tx0 + l15 + dx;
      short8v a = {};
      if (yy >= 0 && yy < 128 && xx >= 0 && xx < 128)
        a = *(const short8v*)&h2t[(ibase + (yy << 7) + xx) * 32 + lk * 8];
      acc = __builtin_amdgcn_mfma_f32_16x16x32_bf16(a, B[tap], acc, 0, 0, 0);
    }
#pragma unroll
    for (int q = 0; q < 4; ++q) {
      int px = tx0 + lk * 4 + q;
      h3t[(ibase + (y << 7) + px) * 16 + l15] = f2us(fmaxf(acc[q] + bias, 0.f));
    }
  }
}

// ---------- conv3 (small path): round-10 VALU version, planar ----------
__global__ __launch_bounds__(256) void conv3_k(const u16* __restrict__ h2c,
                                               const float* __restrict__ wf,
                                               u16* __restrict__ h3c) {
  __shared__ float s_in[8 * 18 * 35];
  int bx = blockIdx.x;
  int n = bx >> 5;
  int rem = bx & 31;
  int y0 = (rem >> 2) << 4;
  int x0 = (rem & 3) << 5;
  int tid = threadIdx.x;
  int r = tid >> 4;
  int c2 = (tid & 15) << 1;
  float acc[16][2];
#pragma unroll
  for (int o = 0; o < 16; ++o) { acc[o][0] = 0.f; acc[o][1] = 0.f; }
#pragma unroll 1
  for (int pass = 0; pass < 4; ++pass) {
    __syncthreads();
    for (int i = tid; i < 4896; i += 256) {
      int icl = i / 612;
      int p = i - icl * 612;
      int py = p / 34, px = p - py * 34;
      int gy = y0 + py - 1, gx = x0 + px - 1;
      float v = 0.f;
      if (gy >= 0 && gy < 128 && gx >= 0 && gx < 128)
        v = us2f(h2c[((long)(n * 32 + pass * 8 + icl) << 14) + (gy << 7) + gx]);
      s_in[(icl * 18 + py) * 35 + px] = v;
    }
    __syncthreads();
#pragma unroll 1
    for (int icl = 0; icl < 8; ++icl) {
      int ic = pass * 8 + icl;
      float a[3][4];
#pragma unroll
      for (int dy = 0; dy < 3; ++dy)
#pragma unroll
        for (int dx = 0; dx < 4; ++dx)
          a[dy][dx] = s_in[(icl * 18 + r + dy) * 35 + c2 + dx];
#pragma unroll
      for (int o = 0; o < 16; ++o) {
        const float* wo = wf + W3 + o * 288 + ic * 9;
        float w0 = wo[0], w1 = wo[1], w2 = wo[2], w3 = wo[3], w4 = wo[4],
              w5 = wo[5], w6 = wo[6], w7 = wo[7], w8 = wo[8];
#pragma unroll
        for (int p = 0; p < 2; ++p)
          acc[o][p] += a[0][p] * w0 + a[0][p + 1] * w1 + a[0][p + 2] * w2 +
                       a[1][p] * w3 + a[1][p + 1] * w4 + a[1][p + 2] * w5 +
                       a[2][p] * w6 + a[2][p + 1] * w7 + a[2][p + 2] * w8;
      }
    }
  }
  int opix = ((y0 + r) << 7) + x0 + c2;
#pragma unroll
  for (int o = 0; o < 16; ++o) {
    float b = wf[B3 + o];
    u32 v = pk2(fmaxf(acc[o][0] + b, 0.f), fmaxf(acc[o][1] + b, 0.f));
    *(u32*)&h3c[((long)(n * 16 + o) << 14) + opix] = v;
  }
}

// ---------- conv4 (big path): NHWC direct, 1 px/thread, no LDS ----------
__global__ __launch_bounds__(256) void conv4n_k(const u16* __restrict__ h3t,
                                                const float* __restrict__ wf,
                                                float* __restrict__ x1f,
                                                void* __restrict__ out0,
                                                const int* __restrict__ flag) {
  int pix = blockIdx.x * 256 + threadIdx.x;
  int loc = pix & 16383;
  int y = loc >> 7, x = loc & 127;
  float acc = wf[B4];
#pragma unroll
  for (int tap = 0; tap < 9; ++tap) {
    int dy = tap / 3 - 1, dx = tap % 3 - 1;
    int yy = y + dy, xx = x + dx;
    if (yy >= 0 && yy < 128 && xx >= 0 && xx < 128) {
      const u16* v = &h3t[((long)pix + (dy << 7) + dx) * 16];
      uint4 a = *(const uint4*)v;
      uint4 b = *(const uint4*)(v + 8);
      u32 vv[8] = {a.x, a.y, a.z, a.w, b.x, b.y, b.z, b.w};
      float s = 0.f;
#pragma unroll
      for (int h = 0; h < 8; ++h) {
        s += us2f((u16)(vv[h] & 0xFFFF)) * wf[W4 + (2 * h) * 9 + tap];
        s += us2f((u16)(vv[h] >> 16)) * wf[W4 + (2 * h + 1) * 9 + tap];
      }
      acc += s;
    }
  }
  x1f[pix] = acc;
  if (*flag) ((u16*)out0)[pix] = f2us(acc);
  else ((float*)out0)[pix] = acc;
}

// ---------- conv4 (small path): planar, LDS version ----------
__global__ __launch_bounds__(256) void conv4_k(const u16* __restrict__ h3c,
                                               const float* __restrict__ wf,
                                               float* __restrict__ x1f,
                                               void* __restrict__ out0,
                                               const int* __restrict__ flag, int img0) {
  __shared__ float s_in[16 * 324];
  int bx = blockIdx.x;
  int n = bx >> 6;
  int ty0 = ((bx >> 3) & 7) << 4, tx0 = (bx & 7) << 4;
  int tid = threadIdx.x;
  for (int i = tid; i < 16 * 324; i += 256) {
    int ic = i / 324, p = i - ic * 324;
    int py = p / 18, px = p - py * 18;
    int gy = ty0 + py - 1, gx = tx0 + px - 1;
    float v = 0.f;
    if (gy >= 0 && gy < 128 && gx >= 0 && gx < 128)
      v = us2f(h3c[((long)(n * 16 + ic) << 14) + (gy << 7) + gx]);
    s_in[i] = v;
  }
  __syncthreads();
  int ty = tid >> 4, tx = tid & 15;
  float acc = wf[B4];
#pragma unroll 1
  for (int ic = 0; ic < 16; ++ic) {
    const float* bi = &s_in[ic * 324 + ty * 18 + tx];
    const float* w = wf + W4 + ic * 9;
    acc += bi[0] * w[0] + bi[1] * w[1] + bi[2] * w[2] + bi[18] * w[3] + bi[19] * w[4] +
           bi[20] * w[5] + bi[36] * w[6] + bi[37] * w[7] + bi[38] * w[8];
  }
  int idx = ((img0 + n) << 14) + ((ty0 + ty) << 7) + (tx0 + tx);
  x1f[idx] = acc;
  if (*flag) ((u16*)out0)[idx] = f2us(acc);
  else ((float*)out0)[idx] = acc;
}

// ---------- graph node features ----------
__global__ void gather_h0_k(const void* __restrict__ pos, const void* __restrict__ xn,
                            const int* __restrict__ batch, const float* __restrict__ x1f,
                            float* __restrict__ h0, const int* __restrict__ flag) {
  int n = blockIdx.x * 256 + threadIdx.x;
  if (n >= NN) return;
  int isbf = *flag;
  float px = ldin(pos, 2 * n, isbf), py = ldin(pos, 2 * n + 1, isbf);
  int ix = (int)rintf((px / 20.0f) * 127.0f);
  int iy = (int)rintf((py / 20.0f) * 127.0f);
  ix = min(max(ix, 0), 127);
  iy = min(max(iy, 0), 127);
  float cn = x1f[(batch[n] << 14) + (iy << 7) + ix];
  float* o = h0 + n * 8;
#pragma unroll
  for (int k = 0; k < 5; ++k) o[k] = ldin(xn, n * 5 + k, isbf);
  o[5] = px;
  o[6] = py;
  o[7] = cn;
}

// ---------- CSR build ----------
__global__ void deg_k(const int* __restrict__ dst, int* __restrict__ deg) {
  int e = blockIdx.x * 256 + threadIdx.x;
  if (e < NE) atomicAdd(&deg[dst[e]], 1);
}
__global__ void scanA_k(const int* __restrict__ deg, int* __restrict__ bsum) {
  __shared__ int s[256];
  int i = blockIdx.x * 256 + threadIdx.x;
  s[threadIdx.x] = (i < NN) ? deg[i] : 0;
  __syncthreads();
  for (int o = 128; o; o >>= 1) {
    if (threadIdx.x < o) s[threadIdx.x] += s[threadIdx.x + o];
    __syncthreads();
  }
  if (threadIdx.x == 0) bsum[blockIdx.x] = s[0];
}
__global__ __launch_bounds__(512) void scanB_k(const int* __restrict__ bsum,
                                               int* __restrict__ bpre) {
  __shared__ int s[512];
  int t = threadIdx.x;
  int v = (t < NBLK) ? bsum[t] : 0;
  s[t] = v;
  __syncthreads();
  for (int o = 1; o < 512; o <<= 1) {
    int u = (t >= o) ? s[t - o] : 0;
    __syncthreads();
    s[t] += u;
    __syncthreads();
  }
  if (t < NBLK) bpre[t] = s[t] - v;
}
__global__ void scanC_k(const int* __restrict__ deg, const int* __restrict__ bpre,
                        int* __restrict__ off, int* __restrict__ curs,
                        float* __restrict__ invd) {
  __shared__ int s[256];
  int i = blockIdx.x * 256 + threadIdx.x, t = threadIdx.x;
  int v = (i < NN) ? deg[i] : 0;
  s[t] = v;
  __syncthreads();
  for (int o = 1; o < 256; o <<= 1) {
    int u = (t >= o) ? s[t - o] : 0;
    __syncthreads();
    s[t] += u;
    __syncthreads();
  }
  if (i < NN) {
    int e = bpre[blockIdx.x] + s[t] - v;
    off[i] = e;
    curs[i] = e;
    invd[i] = 1.0f / fmaxf((float)v, 1.0f);
  }
  if (i == 0) off[NN] = NE;
}
__global__ void fill_k(const int* __restrict__ src, const int* __restrict__ dst,
                       int* __restrict__ curs, int* __restrict__ ss) {
  int e = blockIdx.x * 256 + threadIdx.x;
  if (e < NE) ss[atomicAdd(&curs[dst[e]], 1)] = src[e];
}

// ---------- SAGE layer 0 ----------
__global__ void agg8_k(const float* __restrict__ h0, const int* __restrict__ off,
                       const int* __restrict__ ss, const float* __restrict__ invd,
                       float* __restrict__ m8) {
  int gid = blockIdx.x * 256 + threadIdx.x;
  if (gid >= NN * 8) return;
  int n = gid >> 3, f = gid & 7;
  int e0 = off[n], e1 = off[n + 1];
  float s = 0.f;
  for (int j = e0; j < e1; ++j) s += h0[ss[j] * 8 + f];
  m8[gid] = s * invd[n];
}
__global__ void combine0_k(const float* __restrict__ h0, const float* __restrict__ m8,
                           const float* __restrict__ wl, const float* __restrict__ wr,
                           const float* __restrict__ bs, u16* __restrict__ OUT) {
  int gid = blockIdx.x * 256 + threadIdx.x;
  int n = gid >> 7, fo = gid & 127;
  float acc = bs[fo];
#pragma unroll
  for (int fi = 0; fi < 8; ++fi)
    acc += m8[n * 8 + fi] * wl[fi * 128 + fo] + h0[n * 8 + fi] * wr[fi * 128 + fo];
  OUT[gid] = f2us(fmaxf(acc, 0.f));
}

// ---------- SAGE 128->128: round-13 structure + offset/index prefetch ----------
__global__ __launch_bounds__(256) void sage_mfma_k(
    const u16* __restrict__ X, const int* __restrict__ off, const int* __restrict__ ss,
    const float* __restrict__ invd, const u16* __restrict__ WT,
    const float* __restrict__ bs, u16* __restrict__ OUT) {
  __shared__ __align__(16) u16 sM[32 * 128];  // 8 KB
  int tid = threadIdx.x;
  int nodeBase = blockIdx.x * 32;
  {
    int grp = tid >> 5, t = tid & 31;
    int elane = t >> 3;  // 0..3 edge lanes
    int fg = t & 7;      // 8 f-lanes x 16 features
    int e0s[4], e1s[4], sidx[4];
#pragma unroll
    for (int rep = 0; rep < 4; ++rep) {
      int node = nodeBase + grp * 4 + rep;
      e0s[rep] = off[node];
      e1s[rep] = off[node + 1];
    }
#pragma unroll
    for (int rep = 0; rep < 4; ++rep) {
      int j = e0s[rep] + elane;
      sidx[rep] = (j < e1s[rep]) ? ss[j] : -1;
    }
#pragma unroll 1
    for (int rep = 0; rep < 4; ++rep) {
      int nl = grp * 4 + rep;
      int node = nodeBase + nl;
      float s[16];
#pragma unroll
      for (int k = 0; k < 16; ++k) s[k] = 0.f;
      if (sidx[rep] >= 0) {
        const u16* row = &X[(long)sidx[rep] * 128 + fg * 16];
        ushort4 r0 = *(const ushort4*)row;
        ushort4 r1 = *(const ushort4*)(row + 4);
        ushort4 r2 = *(const ushort4*)(row + 8);
        ushort4 r3 = *(const ushort4*)(row + 12);
        s[0] += us2f(r0.x);  s[1] += us2f(r0.y);  s[2] += us2f(r0.z);  s[3] += us2f(r0.w);
        s[4] += us2f(r1.x);  s[5] += us2f(r1.y);  s[6] += us2f(r1.z);  s[7] += us2f(r1.w);
        s[8] += us2f(r2.x);  s[9] += us2f(r2.y);  s[10] += us2f(r2.z); s[11] += us2f(r2.w);
        s[12] += us2f(r3.x); s[13] += us2f(r3.y); s[14] += us2f(r3.z); s[15] += us2f(r3.w);
      }
      for (int j = e0s[rep] + elane + 4; j < e1s[rep]; j += 4) {
        const u16* row = &X[(long)ss[j] * 128 + fg * 16];
        ushort4 r0 = *(const ushort4*)row;
        ushort4 r1 = *(const ushort4*)(row + 4);
        ushort4 r2 = *(const ushort4*)(row + 8);
        ushort4 r3 = *(const ushort4*)(row + 12);
        s[0] += us2f(r0.x);  s[1] += us2f(r0.y);  s[2] += us2f(r0.z);  s[3] += us2f(r0.w);
        s[4] += us2f(r1.x);  s[5] += us2f(r1.y);  s[6] += us2f(r1.z);  s[7] += us2f(r1.w);
        s[8] += us2f(r2.x);  s[9] += us2f(r2.y);  s[10] += us2f(r2.z); s[11] += us2f(r2.w);
        s[12] += us2f(r3.x); s[13] += us2f(r3.y); s[14] += us2f(r3.z); s[15] += us2f(r3.w);
      }
#pragma unroll
      for (int k = 0; k < 16; ++k) {
        s[k] += __shfl_xor(s[k], 8);
        s[k] += __shfl_xor(s[k], 16);
      }
      if (elane == 0) {
        float iv = invd[node];
        uint4 w0, w1;
        w0.x = pk2(s[0] * iv, s[1] * iv);   w0.y = pk2(s[2] * iv, s[3] * iv);
        w0.z = pk2(s[4] * iv, s[5] * iv);   w0.w = pk2(s[6] * iv, s[7] * iv);
        w1.x = pk2(s[8] * iv, s[9] * iv);   w1.y = pk2(s[10] * iv, s[11] * iv);
        w1.z = pk2(s[12] * iv, s[13] * iv); w1.w = pk2(s[14] * iv, s[15] * iv);
        int f0 = fg * 16;
        int swz = (nl & 7) << 3;
        *(uint4*)&sM[nl * 128 + (f0 ^ swz)] = w0;
        *(uint4*)&sM[nl * 128 + ((f0 + 8) ^ swz)] = w1;
      }
    }
  }
  __syncthreads();
  int wave = tid >> 6, lane = tid & 63;
  if (wave >= 2) return;
  int l15 = lane & 15, lk = lane >> 4;
  int arow = nodeBase + wave * 16 + l15;
  int mrow = wave * 16 + l15;
  f32x4 acc[8] = {};
#pragma unroll 1
  for (int ks = 0; ks < 8; ++ks) {
    short8v a;
    if (ks < 4) {
      a = *(const short8v*)&X[arow * 128 + ks * 32 + lk * 8];
    } else {
      int koff = (ks - 4) * 32 + lk * 8;
      a = *(const short8v*)&sM[mrow * 128 + (koff ^ ((mrow & 7) << 3))];
    }
#pragma unroll
    for (int r = 0; r < 8; ++r) {
      short8v b = *(const short8v*)&WT[(r * 16 + l15) * 256 + ks * 32 + lk * 8];
      acc[r] = __builtin_amdgcn_mfma_f32_16x16x32_bf16(a, b, acc[r], 0, 0, 0);
    }
  }
#pragma unroll
  for (int r = 0; r < 8; ++r) {
    int n = r * 16 + l15;
    float bias = bs[n];
#pragma unroll
    for (int q = 0; q < 4; ++q) {
      int node = nodeBase + wave * 16 + lk * 4 + q;
      OUT[node * 128 + n] = f2us(fmaxf(acc[r][q] + bias, 0.f));
    }
  }
}

// ---------- last layer ----------
__global__ __launch_bounds__(256) void dots_k(const u16* __restrict__ X,
                                              const float* __restrict__ wl,
                                              const float* __restrict__ wr,
                                              float* __restrict__ YL,
                                              float* __restrict__ YR) {
  __shared__ float swl[128], swr[128];
  int tid = threadIdx.x;
  if (tid < 128) swl[tid] = wl[tid];
  else swr[tid - 128] = wr[tid - 128];
  __syncthreads();
  int g = blockIdx.x * 8 + (tid >> 5);
  int t = tid & 31, f0 = t * 4;
  if (g >= NN) return;
  ushort4 r = *(const ushort4*)&X[g * 128 + f0];
  float x0 = us2f(r.x), x1 = us2f(r.y), x2 = us2f(r.z), x3 = us2f(r.w);
  float pl = x0 * swl[f0] + x1 * swl[f0 + 1] + x2 * swl[f0 + 2] + x3 * swl[f0 + 3];
  float pr = x0 * swr[f0] + x1 * swr[f0 + 1] + x2 * swr[f0 + 2] + x3 * swr[f0 + 3];
#pragma unroll
  for (int o = 16; o; o >>= 1) {
    pl += __shfl_xor(pl, o);
    pr += __shfl_xor(pr, o);
  }
  if (t == 0) {
    YL[g] = pl;
    YR[g] = pr;
  }
}

__global__ void last_k(const float* __restrict__ YL, const float* __restrict__ YR,
                       const int* __restrict__ off, const int* __restrict__ ss,
                       const float* __restrict__ invd, const float* __restrict__ bs,
                       void* __restrict__ gout, const int* __restrict__ flag) {
  int n = blockIdx.x * 256 + threadIdx.x;
  if (n >= NN) return;
  int e0 = off[n], e1 = off[n + 1];
  float s0 = 0.f, s1 = 0.f;
  int j = e0;
  for (; j + 1 < e1; j += 2) {
    s0 += YL[ss[j]];
    s1 += YL[ss[j + 1]];
  }
  if (j < e1) s0 += YL[ss[j]];
  float v = YR[n] + (s0 + s1) * invd[n] + bs[0];
  if (*flag) ((u16*)gout)[1048576 + n] = f2us(v);
  else ((float*)gout)[1048576 + n] = v;
}

// ---------- diagnostic ----------
__global__ void diag_k(u16* out, int n, u16 v) {
  int i = blockIdx.x * 256 + threadIdx.x;
  if (i < n) out[i] = v;
}

extern "C" void kernel_launch(void* const* d_in, const int* in_sizes, int n_in,
                              void* d_out, int out_size, void* d_ws, size_t ws_size,
                              hipStream_t stream) {
  const void* x128 = d_in[0];
  const void* xn = d_in[1];
  const void* pos = d_in[2];
  const int* eidx = (const int*)d_in[3];
  const int* batch = (const int*)d_in[4];
  const int* esrc = eidx;
  const int* edst = eidx + NE;

  const size_t REQUIRED = 66910000;
  const size_t REQUIRED_BIG = 210640000;
  if (ws_size < REQUIRED) {
    union { float f; u32 i; } c;
    c.f = (float)(ws_size >> 20);
    diag_k<<<(out_size + 255) / 256, 256, 0, stream>>>((u16*)d_out, out_size,
                                                       (u16)(c.i >> 16));
    return;
  }
  const bool big = (ws_size >= REQUIRED_BIG);

  char* ws = (char*)d_ws;
  float* x1f = (float*)ws;                   // dead after gather_h0
  u16* WT1 = (u16*)(ws + 0);                 // OVERLAYS x1f: write only after gather_h0!
  u16* WT2 = (u16*)(ws + 65536);
  float* YL = (float*)(ws + 131072);
  float* YR = (float*)(ws + 531072);
  u16* h1c = (u16*)(ws + 4194304);
  u16* h2c = big ? (u16*)(ws + 71303168) : (u16*)(ws + 20971520);
  u16* h3c = h1c;
  u16* WT3 = (u16*)(ws + 138412032);         // big-path region only
  u16* WT2M = (u16*)(ws + 138421248);
  float* h0 = (float*)(ws + 4194304);
  float* m8 = (float*)(ws + 7394304);
  u16* HA = (u16*)(ws + 10594304);
  u16* HB = (u16*)(ws + 36194304);
  size_t base = big ? 205520896UL : 61794304UL;
  float* wf = (float*)(ws + base);
  int* deg = (int*)(ws + base + 312320);
  float* invd = (float*)(ws + base + 712320);
  int* noff = (int*)(ws + base + 1112320);
  int* curs = (int*)(ws + base + 1512576);
  int* ssrc = (int*)(ws + base + 1912576);
  int* bsum = (int*)(ws + base + 5112576);
  int* bpre = (int*)(ws + base + 5114368);
  int* flag = (int*)(ws + base + 5116160);

  detect_k<<<1, 64, 0, stream>>>(x128, flag);

  Jobs jb;
  const int jin[19] = {6, 7, 8, 9, 10, 11, 12, 13, 14, 15, 16, 17, 18, 19, 20, 21, 22, 23, 24};
  const int joff[19] = {B1, W2, B2, W3, B3, W4, B4, WL0, WR0, BS0, WL1, WR1, BS1,
                        WL2, WR2, BS2, WL3, WR3, BS3};
  const int jn[19] = {16, 4608, 32, 4608, 16, 144, 1, 1024, 1024, 128, 16384, 16384,
                      128, 16384, 16384, 128, 128, 128, 1};
  for (int j = 0; j < 19; ++j) { jb.p[j] = d_in[jin[j]]; jb.off[j] = joff[j]; jb.n[j] = jn[j]; }
  cvt_all_k<<<dim3(64, 19), 256, 0, stream>>>(jb, wf, flag);
  w1eff_k<<<1, 256, 0, stream>>>(d_in[5], wf, flag);

  if (big) {
    wcat3_k<<<18, 256, 0, stream>>>(wf, WT3);
    wcat2m_k<<<20, 256, 0, stream>>>(wf, WT2M);
    conv1_k<true><<<4096, 256, 0, stream>>>(x128, wf, h1c, flag, 0);
    conv2m_k<<<4096, 256, 0, stream>>>(h1c, WT2M, wf, h2c);
    conv3m_k<<<4096, 256, 0, stream>>>(h2c, WT3, wf, h3c);
    conv4n_k<<<4096, 256, 0, stream>>>(h3c, wf, x1f, d_out, flag);
  } else {
    for (int c = 0; c < 4; ++c) {
      int img0 = c * 16;
      conv1_k<false><<<1024, 256, 0, stream>>>(x128, wf, h1c, flag, img0);
      conv2_k<<<512, 256, 0, stream>>>(h1c, wf, h2c);
      conv3_k<<<512, 256, 0, stream>>>(h2c, wf, h3c);
      conv4_k<<<1024, 256, 0, stream>>>(h3c, wf, x1f, d_out, flag, img0);
    }
  }

  gather_h0_k<<<(NN + 255) / 256, 256, 0, stream>>>(pos, xn, batch, x1f, h0, flag);
  // x1f now dead -> safe to build WT1/WT2 in its region
  wcat_k<<<128, 256, 0, stream>>>(wf, WT1, WT2);

  hipMemsetAsync(deg, 0, NN * sizeof(int), stream);
  deg_k<<<(NE + 255) / 256, 256, 0, stream>>>(edst, deg);
  scanA_k<<<NBLK, 256, 0, stream>>>(deg, bsum);
  scanB_k<<<1, 512, 0, stream>>>(bsum, bpre);
  scanC_k<<<NBLK, 256, 0, stream>>>(deg, bpre, noff, curs, invd);
  fill_k<<<(NE + 255) / 256, 256, 0, stream>>>(esrc, edst, curs, ssrc);

  agg8_k<<<(NN * 8 + 255) / 256, 256, 0, stream>>>(h0, noff, ssrc, invd, m8);
  combine0_k<<<NN * 128 / 256, 256, 0, stream>>>(h0, m8, wf + WL0, wf + WR0, wf + BS0, HA);
  sage_mfma_k<<<3125, 256, 0, stream>>>(HA, noff, ssrc, invd, WT1, wf + BS1, HB);
  sage_mfma_k<<<3125, 256, 0, stream>>>(HB, noff, ssrc, invd, WT2, wf + BS2, HA);
  dots_k<<<12500, 256, 0, stream>>>(HA, wf + WL3, wf + WR3, YL, YR);
  last_k<<<(NN + 255) / 256, 256, 0, stream>>>(YL, YR, noff, ssrc, invd, wf + BS3,
                                               d_out, flag);
}

// Round 17
// 469.219 us; speedup vs baseline: 1.1152x; 1.0400x over previous
//
#include <hip/hip_runtime.h>
#include <hip/hip_bf16.h>

#define NN 100000
#define NE 800000
#define NBLK 391  // ceil(NN/256)

typedef unsigned short u16;
typedef unsigned int u32;
typedef __attribute__((ext_vector_type(8))) short short8v;
typedef __attribute__((ext_vector_type(4))) float f32x4;

// wf offsets
enum {
  W1E = 0, B1 = 144, W2 = 160, B2 = 4768, W3 = 4800, B3 = 9408, W4 = 9424,
  B4 = 9568, WL0 = 9600, WR0 = 10624, BS0 = 11648, WL1 = 11776, WR1 = 28160,
  BS1 = 44544, WL2 = 44672, WR2 = 61056, BS2 = 77440, WL3 = 77568, WR3 = 77696,
  BS3 = 77824
};

__device__ __forceinline__ float us2f(u16 u) {
  union { u32 i; float f; } c; c.i = ((u32)u) << 16; return c.f;
}
__device__ __forceinline__ u16 f2us(float f) {
  union { __hip_bfloat16 h; u16 u; } c; c.h = __float2bfloat16(f); return c.u;
}
__device__ __forceinline__ u32 pk2(float a, float b) {
  return (u32)f2us(a) | ((u32)f2us(b) << 16);
}
__device__ __forceinline__ float ldin(const void* p, long i, int isbf) {
  return isbf ? us2f(((const u16*)p)[i]) : ((const float*)p)[i];
}

// ---------- dtype detection ----------
__global__ void detect_k(const void* x, int* flag) {
  if (threadIdx.x == 0) {
    const u16* u = (const u16*)x;
    int good = 0;
    for (int i = 0; i < 256; ++i) {
      int e = (u[2 * i] >> 7) & 0xFF;
      if (e >= 64 && e <= 141) ++good;
    }
    *flag = (good >= 200) ? 1 : 0;
  }
}

// ---------- weight conversion ----------
struct Jobs {
  const void* p[19];
  int off[19];
  int n[19];
};
__global__ void cvt_all_k(Jobs jb, float* __restrict__ wf, const int* __restrict__ flag) {
  int j = blockIdx.y;
  int i = blockIdx.x * 256 + threadIdx.x;
  int isbf = *flag;
  if (i < jb.n[j]) wf[jb.off[j] + i] = ldin(jb.p[j], i, isbf);
}

__global__ void w1eff_k(const void* __restrict__ w1, float* __restrict__ wf,
                        const int* __restrict__ flag) {
  int i = threadIdx.x;
  int isbf = *flag;
  if (i < 144) {
    int oc = i / 9, k = i - oc * 9;
    float s = 0.f;
#pragma unroll
    for (int ic = 0; ic < 6; ++ic) s += ldin(w1, (oc * 6 + ic) * 9 + k, isbf);
    wf[i] = s;
  }
}

// WT1/WT2: launched AFTER gather_h0 (x1f region dead by then!)
__global__ void wcat_k(const float* __restrict__ wf, u16* __restrict__ WT1,
                       u16* __restrict__ WT2) {
  int i = blockIdx.x * 256 + threadIdx.x;
  if (i < 32768) {
    int n = i >> 8, k = i & 255;
    WT1[i] = f2us(wf[(k < 128 ? WR1 : WL1) + (k & 127) * 128 + n]);
    WT2[i] = f2us(wf[(k < 128 ? WR2 : WL2) + (k & 127) * 128 + n]);
  }
}

// WT3[tap][oc=16][ic=32] (big-path buffer region only)
__global__ void wcat3_k(const float* __restrict__ wf, u16* __restrict__ WT3) {
  int i = blockIdx.x * 256 + threadIdx.x;
  if (i < 4608) {
    int tap = i >> 9;
    int rem = i & 511;
    int oc = rem >> 5, ic = rem & 31;
    WT3[i] = f2us(wf[W3 + oc * 288 + ic * 9 + tap]);
  }
}

// WT2M[(pair*2+half)*16+oc][k32]
__global__ void wcat2m_k(const float* __restrict__ wf, u16* __restrict__ W) {
  int i = blockIdx.x * 256 + threadIdx.x;
  if (i < 5120) {
    int k = i & 31;
    int oc = (i >> 5) & 15;
    int h = (i >> 9) & 1;
    int p = i >> 10;
    int tap = p * 2 + (k >> 4);
    int ic = k & 15;
    float v = (tap <= 8) ? wf[W2 + (h * 16 + oc) * 144 + ic * 9 + tap] : 0.f;
    W[i] = f2us(v);
  }
}

// ---------- conv1: 1->16 ch, 1 px/thread; bf16 out (NHWC or planar) ----------
template <bool NHWC>
__global__ __launch_bounds__(256) void conv1_k(const void* __restrict__ x128,
                                               const float* __restrict__ wf,
                                               u16* __restrict__ h1,
                                               const int* __restrict__ flag, int img0) {
  __shared__ float s_in[324];
  __shared__ float s_w[160];
  int bx = blockIdx.x;
  int n = bx >> 6;
  int ty0 = ((bx >> 3) & 7) << 4, tx0 = (bx & 7) << 4;
  int tid = threadIdx.x;
  int isbf = *flag;
  if (tid < 160) s_w[tid] = wf[tid];
  for (int i = tid; i < 324; i += 256) {
    int py = i / 18, px = i - py * 18;
    int gy = ty0 + py - 1, gx = tx0 + px - 1;
    float v = 0.f;
    if (gy >= 0 && gy < 128 && gx >= 0 && gx < 128)
      v = ldin(x128, ((long)(img0 + n) << 14) + (gy << 7) + gx, isbf);
    s_in[i] = v;
  }
  __syncthreads();
  int ty = tid >> 4, tx = tid & 15;
  const float* bi = &s_in[ty * 18 + tx];
  float a0 = bi[0], a1 = bi[1], a2 = bi[2], a3 = bi[18], a4 = bi[19], a5 = bi[20],
        a6 = bi[36], a7 = bi[37], a8 = bi[38];
  int opix = ((ty0 + ty) << 7) + (tx0 + tx);
  float rv[16];
#pragma unroll
  for (int oc = 0; oc < 16; ++oc) {
    const float* w = s_w + oc * 9;
    float acc = s_w[144 + oc] + a0 * w[0] + a1 * w[1] + a2 * w[2] + a3 * w[3] +
                a4 * w[4] + a5 * w[5] + a6 * w[6] + a7 * w[7] + a8 * w[8];
    rv[oc] = fmaxf(acc, 0.f);
  }
  if (NHWC) {
    long base = (((long)(img0 + n) << 14) + opix) * 16;
    uint4 w0, w1;
    w0.x = pk2(rv[0], rv[1]);   w0.y = pk2(rv[2], rv[3]);
    w0.z = pk2(rv[4], rv[5]);   w0.w = pk2(rv[6], rv[7]);
    w1.x = pk2(rv[8], rv[9]);   w1.y = pk2(rv[10], rv[11]);
    w1.z = pk2(rv[12], rv[13]); w1.w = pk2(rv[14], rv[15]);
    *(uint4*)&h1[base] = w0;
    *(uint4*)&h1[base + 8] = w1;
  } else {
#pragma unroll
    for (int oc = 0; oc < 16; ++oc)
      h1[((long)(n * 16 + oc) << 14) + opix] = f2us(rv[oc]);
  }
}

// ---------- conv2 (big path): paired-tap MFMA implicit GEMM, NHWC->NHWC ----------
__global__ __launch_bounds__(256) void conv2m_k(const u16* __restrict__ h1t,
                                                const u16* __restrict__ WT2M,
                                                const float* __restrict__ wf,
                                                u16* __restrict__ h2t) {
  int bx = blockIdx.x;
  int img = bx >> 6;
  int t = bx & 63;
  int ty0 = (t >> 3) << 4, tx0 = (t & 7) << 4;
  int tid = threadIdx.x;
  int wave = tid >> 6, lane = tid & 63;
  int l15 = lane & 15, lk = lane >> 4;
  long ibase = (long)img << 14;
  short8v B[5][2];
#pragma unroll
  for (int p = 0; p < 5; ++p)
#pragma unroll
    for (int h = 0; h < 2; ++h)
      B[p][h] = *(const short8v*)&WT2M[(((p * 2 + h) << 4) + l15) * 32 + lk * 8];
  float bias0 = wf[B2 + l15];
  float bias1 = wf[B2 + 16 + l15];
#pragma unroll 1
  for (int rg = 0; rg < 4; ++rg) {
    int y = ty0 + wave * 4 + rg;
    f32x4 acc0 = {}, acc1 = {};
#pragma unroll
    for (int p = 0; p < 5; ++p) {
      int tap = min(p * 2 + (lk >> 1), 8);
      int dy = tap / 3 - 1, dx = tap % 3 - 1;
      int yy = y + dy, xx = tx0 + l15 + dx;
      short8v a = {};
      if (yy >= 0 && yy < 128 && xx >= 0 && xx < 128)
        a = *(const short8v*)&h1t[(ibase + (yy << 7) + xx) * 16 + (lk & 1) * 8];
      acc0 = __builtin_amdgcn_mfma_f32_16x16x32_bf16(a, B[p][0], acc0, 0, 0, 0);
      acc1 = __builtin_amdgcn_mfma_f32_16x16x32_bf16(a, B[p][1], acc1, 0, 0, 0);
    }
#pragma unroll
    for (int q = 0; q < 4; ++q) {
      int px = tx0 + lk * 4 + q;
      long o = (ibase + (y << 7) + px) * 32;
      h2t[o + l15] = f2us(fmaxf(acc0[q] + bias0, 0.f));
      h2t[o + 16 + l15] = f2us(fmaxf(acc1[q] + bias1, 0.f));
    }
  }
}

// ---------- conv2 (small path): round-7 VALU version, planar ----------
__global__ __launch_bounds__(256) void conv2_k(const u16* __restrict__ h1c,
                                               const float* __restrict__ wf,
                                               u16* __restrict__ out) {
  __shared__ float s_in[8 * 18 * 35];
  int bx = blockIdx.x;
  int n = bx >> 5;
  int rem = bx & 31;
  int y0 = (rem >> 2) << 4;
  int x0 = (rem & 3) << 5;
  int tid = threadIdx.x;
  int ocb = __builtin_amdgcn_readfirstlane((tid >> 7) << 4);
  int r = (tid >> 3) & 15;
  int c4 = (tid & 7) << 2;
  float acc[16][4];
#pragma unroll
  for (int o = 0; o < 16; ++o)
#pragma unroll
    for (int p = 0; p < 4; ++p) acc[o][p] = 0.f;
#pragma unroll 1
  for (int pass = 0; pass < 2; ++pass) {
    __syncthreads();
    for (int i = tid; i < 4896; i += 256) {
      int icl = i / 612;
      int p = i - icl * 612;
      int py = p / 34, px = p - py * 34;
      int gy = y0 + py - 1, gx = x0 + px - 1;
      float v = 0.f;
      if (gy >= 0 && gy < 128 && gx >= 0 && gx < 128)
        v = us2f(h1c[((long)(n * 16 + pass * 8 + icl) << 14) + (gy << 7) + gx]);
      s_in[(icl * 18 + py) * 35 + px] = v;
    }
    __syncthreads();
#pragma unroll 1
    for (int icl = 0; icl < 8; ++icl) {
      int ic = pass * 8 + icl;
      float a[3][6];
#pragma unroll
      for (int dy = 0; dy < 3; ++dy)
#pragma unroll
        for (int dx = 0; dx < 6; ++dx)
          a[dy][dx] = s_in[(icl * 18 + r + dy) * 35 + c4 + dx];
      const float* wb = wf + W2 + ic * 9;
#pragma unroll
      for (int o = 0; o < 16; ++o) {
        const float* wo = wb + (ocb + o) * 144;
        float w0 = wo[0], w1 = wo[1], w2 = wo[2], w3 = wo[3], w4 = wo[4],
              w5 = wo[5], w6 = wo[6], w7 = wo[7], w8 = wo[8];
#pragma unroll
        for (int p = 0; p < 4; ++p)
          acc[o][p] += a[0][p] * w0 + a[0][p + 1] * w1 + a[0][p + 2] * w2 +
                       a[1][p] * w3 + a[1][p + 1] * w4 + a[1][p + 2] * w5 +
                       a[2][p] * w6 + a[2][p + 1] * w7 + a[2][p + 2] * w8;
      }
    }
  }
  int opix = ((y0 + r) << 7) + x0 + c4;
#pragma unroll
  for (int o = 0; o < 16; ++o) {
    float b = wf[B2 + ocb + o];
    ushort4 v;
    v.x = f2us(fmaxf(acc[o][0] + b, 0.f));
    v.y = f2us(fmaxf(acc[o][1] + b, 0.f));
    v.z = f2us(fmaxf(acc[o][2] + b, 0.f));
    v.w = f2us(fmaxf(acc[o][3] + b, 0.f));
    *(ushort4*)&out[((long)(n * 32 + ocb + o) << 14) + opix] = v;
  }
}

// ---------- conv3 (big path): 9-tap MFMA implicit GEMM, NHWC ----------
__global__ __launch_bounds__(256) void conv3m_k(const u16* __restrict__ h2t,
                                                const u16* __restrict__ WT3,
                                                const float* __restrict__ wf,
                                                u16* __restrict__ h3t) {
  int bx = blockIdx.x;
  int img = bx >> 6;
  int t = bx & 63;
  int ty0 = (t >> 3) << 4, tx0 = (t & 7) << 4;
  int tid = threadIdx.x;
  int wave = tid >> 6, lane = tid & 63;
  int l15 = lane & 15, lk = lane >> 4;
  long ibase = (long)img << 14;
  short8v B[9];
#pragma unroll
  for (int tap = 0; tap < 9; ++tap)
    B[tap] = *(const short8v*)&WT3[tap * 512 + l15 * 32 + lk * 8];
  float bias = wf[B3 + l15];
#pragma unroll 1
  for (int rg = 0; rg < 4; ++rg) {
    int y = ty0 + wave * 4 + rg;
    f32x4 acc = {};
#pragma unroll
    for (int tap = 0; tap < 9; ++tap) {
      int dy = tap / 3 - 1, dx = tap % 3 - 1;
      int yy = y + dy, xx = tx0 + l15 + dx;
      short8v a = {};
      if (yy >= 0 && yy < 128 && xx >= 0 && xx < 128)
        a = *(const short8v*)&h2t[(ibase + (yy << 7) + xx) * 32 + lk * 8];
      acc = __builtin_amdgcn_mfma_f32_16x16x32_bf16(a, B[tap], acc, 0, 0, 0);
    }
#pragma unroll
    for (int q = 0; q < 4; ++q) {
      int px = tx0 + lk * 4 + q;
      h3t[(ibase + (y << 7) + px) * 16 + l15] = f2us(fmaxf(acc[q] + bias, 0.f));
    }
  }
}

// ---------- conv3 (small path): round-10 VALU version, planar ----------
__global__ __launch_bounds__(256) void conv3_k(const u16* __restrict__ h2c,
                                               const float* __restrict__ wf,
                                               u16* __restrict__ h3c) {
  __shared__ float s_in[8 * 18 * 35];
  int bx = blockIdx.x;
  int n = bx >> 5;
  int rem = bx & 31;
  int y0 = (rem >> 2) << 4;
  int x0 = (rem & 3) << 5;
  int tid = threadIdx.x;
  int r = tid >> 4;
  int c2 = (tid & 15) << 1;
  float acc[16][2];
#pragma unroll
  for (int o = 0; o < 16; ++o) { acc[o][0] = 0.f; acc[o][1] = 0.f; }
#pragma unroll 1
  for (int pass = 0; pass < 4; ++pass) {
    __syncthreads();
    for (int i = tid; i < 4896; i += 256) {
      int icl = i / 612;
      int p = i - icl * 612;
      int py = p / 34, px = p - py * 34;
      int gy = y0 + py - 1, gx = x0 + px - 1;
      float v = 0.f;
      if (gy >= 0 && gy < 128 && gx >= 0 && gx < 128)
        v = us2f(h2c[((long)(n * 32 + pass * 8 + icl) << 14) + (gy << 7) + gx]);
      s_in[(icl * 18 + py) * 35 + px] = v;
    }
    __syncthreads();
#pragma unroll 1
    for (int icl = 0; icl < 8; ++icl) {
      int ic = pass * 8 + icl;
      float a[3][4];
#pragma unroll
      for (int dy = 0; dy < 3; ++dy)
#pragma unroll
        for (int dx = 0; dx < 4; ++dx)
          a[dy][dx] = s_in[(icl * 18 + r + dy) * 35 + c2 + dx];
#pragma unroll
      for (int o = 0; o < 16; ++o) {
        const float* wo = wf + W3 + o * 288 + ic * 9;
        float w0 = wo[0], w1 = wo[1], w2 = wo[2], w3 = wo[3], w4 = wo[4],
              w5 = wo[5], w6 = wo[6], w7 = wo[7], w8 = wo[8];
#pragma unroll
        for (int p = 0; p < 2; ++p)
          acc[o][p] += a[0][p] * w0 + a[0][p + 1] * w1 + a[0][p + 2] * w2 +
                       a[1][p] * w3 + a[1][p + 1] * w4 + a[1][p + 2] * w5 +
                       a[2][p] * w6 + a[2][p + 1] * w7 + a[2][p + 2] * w8;
      }
    }
  }
  int opix = ((y0 + r) << 7) + x0 + c2;
#pragma unroll
  for (int o = 0; o < 16; ++o) {
    float b = wf[B3 + o];
    u32 v = pk2(fmaxf(acc[o][0] + b, 0.f), fmaxf(acc[o][1] + b, 0.f));
    *(u32*)&h3c[((long)(n * 16 + o) << 14) + opix] = v;
  }
}

// ---------- conv4 (big path): NHWC direct, 1 px/thread, no LDS ----------
__global__ __launch_bounds__(256) void conv4n_k(const u16* __restrict__ h3t,
                                                const float* __restrict__ wf,
                                                float* __restrict__ x1f,
                                                void* __restrict__ out0,
                                                const int* __restrict__ flag) {
  int pix = blockIdx.x * 256 + threadIdx.x;
  int loc = pix & 16383;
  int y = loc >> 7, x = loc & 127;
  float acc = wf[B4];
#pragma unroll
  for (int tap = 0; tap < 9; ++tap) {
    int dy = tap / 3 - 1, dx = tap % 3 - 1;
    int yy = y + dy, xx = x + dx;
    if (yy >= 0 && yy < 128 && xx >= 0 && xx < 128) {
      const u16* v = &h3t[((long)pix + (dy << 7) + dx) * 16];
      uint4 a = *(const uint4*)v;
      uint4 b = *(const uint4*)(v + 8);
      u32 vv[8] = {a.x, a.y, a.z, a.w, b.x, b.y, b.z, b.w};
      float s = 0.f;
#pragma unroll
      for (int h = 0; h < 8; ++h) {
        s += us2f((u16)(vv[h] & 0xFFFF)) * wf[W4 + (2 * h) * 9 + tap];
        s += us2f((u16)(vv[h] >> 16)) * wf[W4 + (2 * h + 1) * 9 + tap];
      }
      acc += s;
    }
  }
  x1f[pix] = acc;
  if (*flag) ((u16*)out0)[pix] = f2us(acc);
  else ((float*)out0)[pix] = acc;
}

// ---------- conv4 (small path): planar, LDS version ----------
__global__ __launch_bounds__(256) void conv4_k(const u16* __restrict__ h3c,
                                               const float* __restrict__ wf,
                                               float* __restrict__ x1f,
                                               void* __restrict__ out0,
                                               const int* __restrict__ flag, int img0) {
  __shared__ float s_in[16 * 324];
  int bx = blockIdx.x;
  int n = bx >> 6;
  int ty0 = ((bx >> 3) & 7) << 4, tx0 = (bx & 7) << 4;
  int tid = threadIdx.x;
  for (int i = tid; i < 16 * 324; i += 256) {
    int ic = i / 324, p = i - ic * 324;
    int py = p / 18, px = p - py * 18;
    int gy = ty0 + py - 1, gx = tx0 + px - 1;
    float v = 0.f;
    if (gy >= 0 && gy < 128 && gx >= 0 && gx < 128)
      v = us2f(h3c[((long)(n * 16 + ic) << 14) + (gy << 7) + gx]);
    s_in[i] = v;
  }
  __syncthreads();
  int ty = tid >> 4, tx = tid & 15;
  float acc = wf[B4];
#pragma unroll 1
  for (int ic = 0; ic < 16; ++ic) {
    const float* bi = &s_in[ic * 324 + ty * 18 + tx];
    const float* w = wf + W4 + ic * 9;
    acc += bi[0] * w[0] + bi[1] * w[1] + bi[2] * w[2] + bi[18] * w[3] + bi[19] * w[4] +
           bi[20] * w[5] + bi[36] * w[6] + bi[37] * w[7] + bi[38] * w[8];
  }
  int idx = ((img0 + n) << 14) + ((ty0 + ty) << 7) + (tx0 + tx);
  x1f[idx] = acc;
  if (*flag) ((u16*)out0)[idx] = f2us(acc);
  else ((float*)out0)[idx] = acc;
}

// ---------- graph node features ----------
__global__ void gather_h0_k(const void* __restrict__ pos, const void* __restrict__ xn,
                            const int* __restrict__ batch, const float* __restrict__ x1f,
                            float* __restrict__ h0, const int* __restrict__ flag) {
  int n = blockIdx.x * 256 + threadIdx.x;
  if (n >= NN) return;
  int isbf = *flag;
  float px = ldin(pos, 2 * n, isbf), py = ldin(pos, 2 * n + 1, isbf);
  int ix = (int)rintf((px / 20.0f) * 127.0f);
  int iy = (int)rintf((py / 20.0f) * 127.0f);
  ix = min(max(ix, 0), 127);
  iy = min(max(iy, 0), 127);
  float cn = x1f[(batch[n] << 14) + (iy << 7) + ix];
  float* o = h0 + n * 8;
#pragma unroll
  for (int k = 0; k < 5; ++k) o[k] = ldin(xn, n * 5 + k, isbf);
  o[5] = px;
  o[6] = py;
  o[7] = cn;
}

// ---------- CSR build ----------
__global__ void deg_k(const int* __restrict__ dst, int* __restrict__ deg) {
  int e = blockIdx.x * 256 + threadIdx.x;
  if (e < NE) atomicAdd(&deg[dst[e]], 1);
}
__global__ void scanA_k(const int* __restrict__ deg, int* __restrict__ bsum) {
  __shared__ int s[256];
  int i = blockIdx.x * 256 + threadIdx.x;
  s[threadIdx.x] = (i < NN) ? deg[i] : 0;
  __syncthreads();
  for (int o = 128; o; o >>= 1) {
    if (threadIdx.x < o) s[threadIdx.x] += s[threadIdx.x + o];
    __syncthreads();
  }
  if (threadIdx.x == 0) bsum[blockIdx.x] = s[0];
}
__global__ __launch_bounds__(512) void scanB_k(const int* __restrict__ bsum,
                                               int* __restrict__ bpre) {
  __shared__ int s[512];
  int t = threadIdx.x;
  int v = (t < NBLK) ? bsum[t] : 0;
  s[t] = v;
  __syncthreads();
  for (int o = 1; o < 512; o <<= 1) {
    int u = (t >= o) ? s[t - o] : 0;
    __syncthreads();
    s[t] += u;
    __syncthreads();
  }
  if (t < NBLK) bpre[t] = s[t] - v;
}
__global__ void scanC_k(const int* __restrict__ deg, const int* __restrict__ bpre,
                        int* __restrict__ off, int* __restrict__ curs,
                        float* __restrict__ invd) {
  __shared__ int s[256];
  int i = blockIdx.x * 256 + threadIdx.x, t = threadIdx.x;
  int v = (i < NN) ? deg[i] : 0;
  s[t] = v;
  __syncthreads();
  for (int o = 1; o < 256; o <<= 1) {
    int u = (t >= o) ? s[t - o] : 0;
    __syncthreads();
    s[t] += u;
    __syncthreads();
  }
  if (i < NN) {
    int e = bpre[blockIdx.x] + s[t] - v;
    off[i] = e;
    curs[i] = e;
    invd[i] = 1.0f / fmaxf((float)v, 1.0f);
  }
  if (i == 0) off[NN] = NE;
}
__global__ void fill_k(const int* __restrict__ src, const int* __restrict__ dst,
                       int* __restrict__ curs, int* __restrict__ ss) {
  int e = blockIdx.x * 256 + threadIdx.x;
  if (e < NE) ss[atomicAdd(&curs[dst[e]], 1)] = src[e];
}

// ---------- SAGE layer 0 ----------
__global__ void agg8_k(const float* __restrict__ h0, const int* __restrict__ off,
                       const int* __restrict__ ss, const float* __restrict__ invd,
                       float* __restrict__ m8) {
  int gid = blockIdx.x * 256 + threadIdx.x;
  if (gid >= NN * 8) return;
  int n = gid >> 3, f = gid & 7;
  int e0 = off[n], e1 = off[n + 1];
  float s = 0.f;
  for (int j = e0; j < e1; ++j) s += h0[ss[j] * 8 + f];
  m8[gid] = s * invd[n];
}
__global__ void combine0_k(const float* __restrict__ h0, const float* __restrict__ m8,
                           const float* __restrict__ wl, const float* __restrict__ wr,
                           const float* __restrict__ bs, u16* __restrict__ OUT) {
  int gid = blockIdx.x * 256 + threadIdx.x;
  int n = gid >> 7, fo = gid & 127;
  float acc = bs[fo];
#pragma unroll
  for (int fi = 0; fi < 8; ++fi)
    acc += m8[n * 8 + fi] * wl[fi * 128 + fo] + h0[n * 8 + fi] * wr[fi * 128 + fo];
  OUT[gid] = f2us(fmaxf(acc, 0.f));
}

// ---------- SAGE 128->128: 16 nodes/block (grid 6250); prefetch; MFMA wave 0 ----------
__global__ __launch_bounds__(256) void sage_mfma_k(
    const u16* __restrict__ X, const int* __restrict__ off, const int* __restrict__ ss,
    const float* __restrict__ invd, const u16* __restrict__ WT,
    const float* __restrict__ bs, u16* __restrict__ OUT) {
  __shared__ __align__(16) u16 sM[16 * 128];  // 4 KB
  int tid = threadIdx.x;
  int nodeBase = blockIdx.x * 16;  // 6250 * 16 = NN exactly
  {
    int grp = tid >> 5, t = tid & 31;
    int elane = t >> 3;  // 0..3 edge lanes
    int fg = t & 7;      // 8 f-lanes x 16 features
    int e0s[2], e1s[2], sidx[2];
#pragma unroll
    for (int rep = 0; rep < 2; ++rep) {
      int node = nodeBase + grp * 2 + rep;
      e0s[rep] = off[node];
      e1s[rep] = off[node + 1];
    }
#pragma unroll
    for (int rep = 0; rep < 2; ++rep) {
      int j = e0s[rep] + elane;
      sidx[rep] = (j < e1s[rep]) ? ss[j] : -1;
    }
#pragma unroll 1
    for (int rep = 0; rep < 2; ++rep) {
      int nl = grp * 2 + rep;
      int node = nodeBase + nl;
      float s[16];
#pragma unroll
      for (int k = 0; k < 16; ++k) s[k] = 0.f;
      if (sidx[rep] >= 0) {
        const u16* row = &X[(long)sidx[rep] * 128 + fg * 16];
        ushort4 r0 = *(const ushort4*)row;
        ushort4 r1 = *(const ushort4*)(row + 4);
        ushort4 r2 = *(const ushort4*)(row + 8);
        ushort4 r3 = *(const ushort4*)(row + 12);
        s[0] += us2f(r0.x);  s[1] += us2f(r0.y);  s[2] += us2f(r0.z);  s[3] += us2f(r0.w);
        s[4] += us2f(r1.x);  s[5] += us2f(r1.y);  s[6] += us2f(r1.z);  s[7] += us2f(r1.w);
        s[8] += us2f(r2.x);  s[9] += us2f(r2.y);  s[10] += us2f(r2.z); s[11] += us2f(r2.w);
        s[12] += us2f(r3.x); s[13] += us2f(r3.y); s[14] += us2f(r3.z); s[15] += us2f(r3.w);
      }
      for (int j = e0s[rep] + elane + 4; j < e1s[rep]; j += 4) {
        const u16* row = &X[(long)ss[j] * 128 + fg * 16];
        ushort4 r0 = *(const ushort4*)row;
        ushort4 r1 = *(const ushort4*)(row + 4);
        ushort4 r2 = *(const ushort4*)(row + 8);
        ushort4 r3 = *(const ushort4*)(row + 12);
        s[0] += us2f(r0.x);  s[1] += us2f(r0.y);  s[2] += us2f(r0.z);  s[3] += us2f(r0.w);
        s[4] += us2f(r1.x);  s[5] += us2f(r1.y);  s[6] += us2f(r1.z);  s[7] += us2f(r1.w);
        s[8] += us2f(r2.x);  s[9] += us2f(r2.y);  s[10] += us2f(r2.z); s[11] += us2f(r2.w);
        s[12] += us2f(r3.x); s[13] += us2f(r3.y); s[14] += us2f(r3.z); s[15] += us2f(r3.w);
      }
#pragma unroll
      for (int k = 0; k < 16; ++k) {
        s[k] += __shfl_xor(s[k], 8);
        s[k] += __shfl_xor(s[k], 16);
      }
      if (elane == 0) {
        float iv = invd[node];
        uint4 w0, w1;
        w0.x = pk2(s[0] * iv, s[1] * iv);   w0.y = pk2(s[2] * iv, s[3] * iv);
        w0.z = pk2(s[4] * iv, s[5] * iv);   w0.w = pk2(s[6] * iv, s[7] * iv);
        w1.x = pk2(s[8] * iv, s[9] * iv);   w1.y = pk2(s[10] * iv, s[11] * iv);
        w1.z = pk2(s[12] * iv, s[13] * iv); w1.w = pk2(s[14] * iv, s[15] * iv);
        int f0 = fg * 16;
        int swz = (nl & 7) << 3;
        *(uint4*)&sM[nl * 128 + (f0 ^ swz)] = w0;
        *(uint4*)&sM[nl * 128 + ((f0 + 8) ^ swz)] = w1;
      }
    }
  }
  __syncthreads();
  if (tid >= 64) return;  // phase 2: wave 0 handles all 16 nodes
  int lane = tid;
  int l15 = lane & 15, lk = lane >> 4;
  int arow = nodeBase + l15;
  int mrow = l15;
  f32x4 acc[8] = {};
#pragma unroll 1
  for (int ks = 0; ks < 8; ++ks) {
    short8v a;
    if (ks < 4) {
      a = *(const short8v*)&X[arow * 128 + ks * 32 + lk * 8];
    } else {
      int koff = (ks - 4) * 32 + lk * 8;
      a = *(const short8v*)&sM[mrow * 128 + (koff ^ ((mrow & 7) << 3))];
    }
#pragma unroll
    for (int r = 0; r < 8; ++r) {
      short8v b = *(const short8v*)&WT[(r * 16 + l15) * 256 + ks * 32 + lk * 8];
      acc[r] = __builtin_amdgcn_mfma_f32_16x16x32_bf16(a, b, acc[r], 0, 0, 0);
    }
  }
#pragma unroll
  for (int r = 0; r < 8; ++r) {
    int n = r * 16 + l15;
    float bias = bs[n];
#pragma unroll
    for (int q = 0; q < 4; ++q) {
      int node = nodeBase + lk * 4 + q;
      OUT[node * 128 + n] = f2us(fmaxf(acc[r][q] + bias, 0.f));
    }
  }
}

// ---------- last layer ----------
__global__ __launch_bounds__(256) void dots_k(const u16* __restrict__ X,
                                              const float* __restrict__ wl,
                                              const float* __restrict__ wr,
                                              float* __restrict__ YL,
                                              float* __restrict__ YR) {
  __shared__ float swl[128], swr[128];
  int tid = threadIdx.x;
  if (tid < 128) swl[tid] = wl[tid];
  else swr[tid - 128] = wr[tid - 128];
  __syncthreads();
  int g = blockIdx.x * 8 + (tid >> 5);
  int t = tid & 31, f0 = t * 4;
  if (g >= NN) return;
  ushort4 r = *(const ushort4*)&X[g * 128 + f0];
  float x0 = us2f(r.x), x1 = us2f(r.y), x2 = us2f(r.z), x3 = us2f(r.w);
  float pl = x0 * swl[f0] + x1 * swl[f0 + 1] + x2 * swl[f0 + 2] + x3 * swl[f0 + 3];
  float pr = x0 * swr[f0] + x1 * swr[f0 + 1] + x2 * swr[f0 + 2] + x3 * swr[f0 + 3];
#pragma unroll
  for (int o = 16; o; o >>= 1) {
    pl += __shfl_xor(pl, o);
    pr += __shfl_xor(pr, o);
  }
  if (t == 0) {
    YL[g] = pl;
    YR[g] = pr;
  }
}

__global__ void last_k(const float* __restrict__ YL, const float* __restrict__ YR,
                       const int* __restrict__ off, const int* __restrict__ ss,
                       const float* __restrict__ invd, const float* __restrict__ bs,
                       void* __restrict__ gout, const int* __restrict__ flag) {
  int n = blockIdx.x * 256 + threadIdx.x;
  if (n >= NN) return;
  int e0 = off[n], e1 = off[n + 1];
  float s0 = 0.f, s1 = 0.f;
  int j = e0;
  for (; j + 1 < e1; j += 2) {
    s0 += YL[ss[j]];
    s1 += YL[ss[j + 1]];
  }
  if (j < e1) s0 += YL[ss[j]];
  float v = YR[n] + (s0 + s1) * invd[n] + bs[0];
  if (*flag) ((u16*)gout)[1048576 + n] = f2us(v);
  else ((float*)gout)[1048576 + n] = v;
}

// ---------- diagnostic ----------
__global__ void diag_k(u16* out, int n, u16 v) {
  int i = blockIdx.x * 256 + threadIdx.x;
  if (i < n) out[i] = v;
}

extern "C" void kernel_launch(void* const* d_in, const int* in_sizes, int n_in,
                              void* d_out, int out_size, void* d_ws, size_t ws_size,
                              hipStream_t stream) {
  const void* x128 = d_in[0];
  const void* xn = d_in[1];
  const void* pos = d_in[2];
  const int* eidx = (const int*)d_in[3];
  const int* batch = (const int*)d_in[4];
  const int* esrc = eidx;
  const int* edst = eidx + NE;

  const size_t REQUIRED = 66910000;
  const size_t REQUIRED_BIG = 210640000;
  if (ws_size < REQUIRED) {
    union { float f; u32 i; } c;
    c.f = (float)(ws_size >> 20);
    diag_k<<<(out_size + 255) / 256, 256, 0, stream>>>((u16*)d_out, out_size,
                                                       (u16)(c.i >> 16));
    return;
  }
  const bool big = (ws_size >= REQUIRED_BIG);

  char* ws = (char*)d_ws;
  float* x1f = (float*)ws;                   // dead after gather_h0
  u16* WT1 = (u16*)(ws + 0);                 // OVERLAYS x1f: write only after gather_h0!
  u16* WT2 = (u16*)(ws + 65536);
  float* YL = (float*)(ws + 131072);
  float* YR = (float*)(ws + 531072);
  u16* h1c = (u16*)(ws + 4194304);
  u16* h2c = big ? (u16*)(ws + 71303168) : (u16*)(ws + 20971520);
  u16* h3c = h1c;
  u16* WT3 = (u16*)(ws + 138412032);         // big-path region only
  u16* WT2M = (u16*)(ws + 138421248);
  float* h0 = (float*)(ws + 4194304);
  float* m8 = (float*)(ws + 7394304);
  u16* HA = (u16*)(ws + 10594304);
  u16* HB = (u16*)(ws + 36194304);
  size_t base = big ? 205520896UL : 61794304UL;
  float* wf = (float*)(ws + base);
  int* deg = (int*)(ws + base + 312320);
  float* invd = (float*)(ws + base + 712320);
  int* noff = (int*)(ws + base + 1112320);
  int* curs = (int*)(ws + base + 1512576);
  int* ssrc = (int*)(ws + base + 1912576);
  int* bsum = (int*)(ws + base + 5112576);
  int* bpre = (int*)(ws + base + 5114368);
  int* flag = (int*)(ws + base + 5116160);

  detect_k<<<1, 64, 0, stream>>>(x128, flag);

  Jobs jb;
  const int jin[19] = {6, 7, 8, 9, 10, 11, 12, 13, 14, 15, 16, 17, 18, 19, 20, 21, 22, 23, 24};
  const int joff[19] = {B1, W2, B2, W3, B3, W4, B4, WL0, WR0, BS0, WL1, WR1, BS1,
                        WL2, WR2, BS2, WL3, WR3, BS3};
  const int jn[19] = {16, 4608, 32, 4608, 16, 144, 1, 1024, 1024, 128, 16384, 16384,
                      128, 16384, 16384, 128, 128, 128, 1};
  for (int j = 0; j < 19; ++j) { jb.p[j] = d_in[jin[j]]; jb.off[j] = joff[j]; jb.n[j] = jn[j]; }
  cvt_all_k<<<dim3(64, 19), 256, 0, stream>>>(jb, wf, flag);
  w1eff_k<<<1, 256, 0, stream>>>(d_in[5], wf, flag);

  if (big) {
    wcat3_k<<<18, 256, 0, stream>>>(wf, WT3);
    wcat2m_k<<<20, 256, 0, stream>>>(wf, WT2M);
    conv1_k<true><<<4096, 256, 0, stream>>>(x128, wf, h1c, flag, 0);
    conv2m_k<<<4096, 256, 0, stream>>>(h1c, WT2M, wf, h2c);
    conv3m_k<<<4096, 256, 0, stream>>>(h2c, WT3, wf, h3c);
    conv4n_k<<<4096, 256, 0, stream>>>(h3c, wf, x1f, d_out, flag);
  } else {
    for (int c = 0; c < 4; ++c) {
      int img0 = c * 16;
      conv1_k<false><<<1024, 256, 0, stream>>>(x128, wf, h1c, flag, img0);
      conv2_k<<<512, 256, 0, stream>>>(h1c, wf, h2c);
      conv3_k<<<512, 256, 0, stream>>>(h2c, wf, h3c);
      conv4_k<<<1024, 256, 0, stream>>>(h3c, wf, x1f, d_out, flag, img0);
    }
  }

  gather_h0_k<<<(NN + 255) / 256, 256, 0, stream>>>(pos, xn, batch, x1f, h0, flag);
  // x1f now dead -> safe to build WT1/WT2 in its region
  wcat_k<<<128, 256, 0, stream>>>(wf, WT1, WT2);

  hipMemsetAsync(deg, 0, NN * sizeof(int), stream);
  deg_k<<<(NE + 255) / 256, 256, 0, stream>>>(edst, deg);
  scanA_k<<<NBLK, 256, 0, stream>>>(deg, bsum);
  scanB_k<<<1, 512, 0, stream>>>(bsum, bpre);
  scanC_k<<<NBLK, 256, 0, stream>>>(deg, bpre, noff, curs, invd);
  fill_k<<<(NE + 255) / 256, 256, 0, stream>>>(esrc, edst, curs, ssrc);

  agg8_k<<<(NN * 8 + 255) / 256, 256, 0, stream>>>(h0, noff, ssrc, invd, m8);
  combine0_k<<<NN * 128 / 256, 256, 0, stream>>>(h0, m8, wf + WL0, wf + WR0, wf + BS0, HA);
  sage_mfma_k<<<6250, 256, 0, stream>>>(HA, noff, ssrc, invd, WT1, wf + BS1, HB);
  sage_mfma_k<<<6250, 256, 0, stream>>>(HB, noff, ssrc, invd, WT2, wf + BS2, HA);
  dots_k<<<12500, 256, 0, stream>>>(HA, wf + WL3, wf + WR3, YL, YR);
  last_k<<<(NN + 255) / 256, 256, 0, stream>>>(YL, YR, noff, ssrc, invd, wf + BS3,
                                               d_out, flag);
}

// Round 18
// 468.985 us; speedup vs baseline: 1.1158x; 1.0005x over previous
//
#include <hip/hip_runtime.h>
#include <hip/hip_bf16.h>

#define NN 100000
#define NE 800000
#define NBLK 391  // ceil(NN/256)

typedef unsigned short u16;
typedef unsigned int u32;
typedef __attribute__((ext_vector_type(8))) short short8v;
typedef __attribute__((ext_vector_type(4))) float f32x4;

// wf offsets
enum {
  W1E = 0, B1 = 144, W2 = 160, B2 = 4768, W3 = 4800, B3 = 9408, W4 = 9424,
  B4 = 9568, WL0 = 9600, WR0 = 10624, BS0 = 11648, WL1 = 11776, WR1 = 28160,
  BS1 = 44544, WL2 = 44672, WR2 = 61056, BS2 = 77440, WL3 = 77568, WR3 = 77696,
  BS3 = 77824
};

__device__ __forceinline__ float us2f(u16 u) {
  union { u32 i; float f; } c; c.i = ((u32)u) << 16; return c.f;
}
__device__ __forceinline__ u16 f2us(float f) {
  union { __hip_bfloat16 h; u16 u; } c; c.h = __float2bfloat16(f); return c.u;
}
__device__ __forceinline__ u32 pk2(float a, float b) {
  return (u32)f2us(a) | ((u32)f2us(b) << 16);
}
__device__ __forceinline__ float ldin(const void* p, long i, int isbf) {
  return isbf ? us2f(((const u16*)p)[i]) : ((const float*)p)[i];
}

// ---------- dtype detection ----------
__global__ void detect_k(const void* x, int* flag) {
  if (threadIdx.x == 0) {
    const u16* u = (const u16*)x;
    int good = 0;
    for (int i = 0; i < 256; ++i) {
      int e = (u[2 * i] >> 7) & 0xFF;
      if (e >= 64 && e <= 141) ++good;
    }
    *flag = (good >= 200) ? 1 : 0;
  }
}

// ---------- weight conversion ----------
struct Jobs {
  const void* p[19];
  int off[19];
  int n[19];
};
__global__ void cvt_all_k(Jobs jb, float* __restrict__ wf, const int* __restrict__ flag) {
  int j = blockIdx.y;
  int i = blockIdx.x * 256 + threadIdx.x;
  int isbf = *flag;
  if (i < jb.n[j]) wf[jb.off[j] + i] = ldin(jb.p[j], i, isbf);
}

__global__ void w1eff_k(const void* __restrict__ w1, float* __restrict__ wf,
                        const int* __restrict__ flag) {
  int i = threadIdx.x;
  int isbf = *flag;
  if (i < 144) {
    int oc = i / 9, k = i - oc * 9;
    float s = 0.f;
#pragma unroll
    for (int ic = 0; ic < 6; ++ic) s += ldin(w1, (oc * 6 + ic) * 9 + k, isbf);
    wf[i] = s;
  }
}

// WT1/WT2: launched AFTER gather_h0 (x1f region dead by then!)
__global__ void wcat_k(const float* __restrict__ wf, u16* __restrict__ WT1,
                       u16* __restrict__ WT2) {
  int i = blockIdx.x * 256 + threadIdx.x;
  if (i < 32768) {
    int n = i >> 8, k = i & 255;
    WT1[i] = f2us(wf[(k < 128 ? WR1 : WL1) + (k & 127) * 128 + n]);
    WT2[i] = f2us(wf[(k < 128 ? WR2 : WL2) + (k & 127) * 128 + n]);
  }
}

// WT3[tap][oc=16][ic=32] (big-path buffer region only)
__global__ void wcat3_k(const float* __restrict__ wf, u16* __restrict__ WT3) {
  int i = blockIdx.x * 256 + threadIdx.x;
  if (i < 4608) {
    int tap = i >> 9;
    int rem = i & 511;
    int oc = rem >> 5, ic = rem & 31;
    WT3[i] = f2us(wf[W3 + oc * 288 + ic * 9 + tap]);
  }
}

// WT2M[(pair*2+half)*16+oc][k32]
__global__ void wcat2m_k(const float* __restrict__ wf, u16* __restrict__ W) {
  int i = blockIdx.x * 256 + threadIdx.x;
  if (i < 5120) {
    int k = i & 31;
    int oc = (i >> 5) & 15;
    int h = (i >> 9) & 1;
    int p = i >> 10;
    int tap = p * 2 + (k >> 4);
    int ic = k & 15;
    float v = (tap <= 8) ? wf[W2 + (h * 16 + oc) * 144 + ic * 9 + tap] : 0.f;
    W[i] = f2us(v);
  }
}

// ---------- conv1: 1->16 ch, 1 px/thread; bf16 out (NHWC or planar) ----------
template <bool NHWC>
__global__ __launch_bounds__(256) void conv1_k(const void* __restrict__ x128,
                                               const float* __restrict__ wf,
                                               u16* __restrict__ h1,
                                               const int* __restrict__ flag, int img0) {
  __shared__ float s_in[324];
  __shared__ float s_w[160];
  int bx = blockIdx.x;
  int n = bx >> 6;
  int ty0 = ((bx >> 3) & 7) << 4, tx0 = (bx & 7) << 4;
  int tid = threadIdx.x;
  int isbf = *flag;
  if (tid < 160) s_w[tid] = wf[tid];
  for (int i = tid; i < 324; i += 256) {
    int py = i / 18, px = i - py * 18;
    int gy = ty0 + py - 1, gx = tx0 + px - 1;
    float v = 0.f;
    if (gy >= 0 && gy < 128 && gx >= 0 && gx < 128)
      v = ldin(x128, ((long)(img0 + n) << 14) + (gy << 7) + gx, isbf);
    s_in[i] = v;
  }
  __syncthreads();
  int ty = tid >> 4, tx = tid & 15;
  const float* bi = &s_in[ty * 18 + tx];
  float a0 = bi[0], a1 = bi[1], a2 = bi[2], a3 = bi[18], a4 = bi[19], a5 = bi[20],
        a6 = bi[36], a7 = bi[37], a8 = bi[38];
  int opix = ((ty0 + ty) << 7) + (tx0 + tx);
  float rv[16];
#pragma unroll
  for (int oc = 0; oc < 16; ++oc) {
    const float* w = s_w + oc * 9;
    float acc = s_w[144 + oc] + a0 * w[0] + a1 * w[1] + a2 * w[2] + a3 * w[3] +
                a4 * w[4] + a5 * w[5] + a6 * w[6] + a7 * w[7] + a8 * w[8];
    rv[oc] = fmaxf(acc, 0.f);
  }
  if (NHWC) {
    long base = (((long)(img0 + n) << 14) + opix) * 16;
    uint4 w0, w1;
    w0.x = pk2(rv[0], rv[1]);   w0.y = pk2(rv[2], rv[3]);
    w0.z = pk2(rv[4], rv[5]);   w0.w = pk2(rv[6], rv[7]);
    w1.x = pk2(rv[8], rv[9]);   w1.y = pk2(rv[10], rv[11]);
    w1.z = pk2(rv[12], rv[13]); w1.w = pk2(rv[14], rv[15]);
    *(uint4*)&h1[base] = w0;
    *(uint4*)&h1[base + 8] = w1;
  } else {
#pragma unroll
    for (int oc = 0; oc < 16; ++oc)
      h1[((long)(n * 16 + oc) << 14) + opix] = f2us(rv[oc]);
  }
}

// ---------- conv2 (big path): paired-tap MFMA implicit GEMM, NHWC->NHWC ----------
__global__ __launch_bounds__(256) void conv2m_k(const u16* __restrict__ h1t,
                                                const u16* __restrict__ WT2M,
                                                const float* __restrict__ wf,
                                                u16* __restrict__ h2t) {
  int bx = blockIdx.x;
  int img = bx >> 6;
  int t = bx & 63;
  int ty0 = (t >> 3) << 4, tx0 = (t & 7) << 4;
  int tid = threadIdx.x;
  int wave = tid >> 6, lane = tid & 63;
  int l15 = lane & 15, lk = lane >> 4;
  long ibase = (long)img << 14;
  short8v B[5][2];
#pragma unroll
  for (int p = 0; p < 5; ++p)
#pragma unroll
    for (int h = 0; h < 2; ++h)
      B[p][h] = *(const short8v*)&WT2M[(((p * 2 + h) << 4) + l15) * 32 + lk * 8];
  float bias0 = wf[B2 + l15];
  float bias1 = wf[B2 + 16 + l15];
#pragma unroll 1
  for (int rg = 0; rg < 4; ++rg) {
    int y = ty0 + wave * 4 + rg;
    f32x4 acc0 = {}, acc1 = {};
#pragma unroll
    for (int p = 0; p < 5; ++p) {
      int tap = min(p * 2 + (lk >> 1), 8);
      int dy = tap / 3 - 1, dx = tap % 3 - 1;
      int yy = y + dy, xx = tx0 + l15 + dx;
      short8v a = {};
      if (yy >= 0 && yy < 128 && xx >= 0 && xx < 128)
        a = *(const short8v*)&h1t[(ibase + (yy << 7) + xx) * 16 + (lk & 1) * 8];
      acc0 = __builtin_amdgcn_mfma_f32_16x16x32_bf16(a, B[p][0], acc0, 0, 0, 0);
      acc1 = __builtin_amdgcn_mfma_f32_16x16x32_bf16(a, B[p][1], acc1, 0, 0, 0);
    }
#pragma unroll
    for (int q = 0; q < 4; ++q) {
      int px = tx0 + lk * 4 + q;
      long o = (ibase + (y << 7) + px) * 32;
      h2t[o + l15] = f2us(fmaxf(acc0[q] + bias0, 0.f));
      h2t[o + 16 + l15] = f2us(fmaxf(acc1[q] + bias1, 0.f));
    }
  }
}

// ---------- conv2 (small path): round-7 VALU version, planar ----------
__global__ __launch_bounds__(256) void conv2_k(const u16* __restrict__ h1c,
                                               const float* __restrict__ wf,
                                               u16* __restrict__ out) {
  __shared__ float s_in[8 * 18 * 35];
  int bx = blockIdx.x;
  int n = bx >> 5;
  int rem = bx & 31;
  int y0 = (rem >> 2) << 4;
  int x0 = (rem & 3) << 5;
  int tid = threadIdx.x;
  int ocb = __builtin_amdgcn_readfirstlane((tid >> 7) << 4);
  int r = (tid >> 3) & 15;
  int c4 = (tid & 7) << 2;
  float acc[16][4];
#pragma unroll
  for (int o = 0; o < 16; ++o)
#pragma unroll
    for (int p = 0; p < 4; ++p) acc[o][p] = 0.f;
#pragma unroll 1
  for (int pass = 0; pass < 2; ++pass) {
    __syncthreads();
    for (int i = tid; i < 4896; i += 256) {
      int icl = i / 612;
      int p = i - icl * 612;
      int py = p / 34, px = p - py * 34;
      int gy = y0 + py - 1, gx = x0 + px - 1;
      float v = 0.f;
      if (gy >= 0 && gy < 128 && gx >= 0 && gx < 128)
        v = us2f(h1c[((long)(n * 16 + pass * 8 + icl) << 14) + (gy << 7) + gx]);
      s_in[(icl * 18 + py) * 35 + px] = v;
    }
    __syncthreads();
#pragma unroll 1
    for (int icl = 0; icl < 8; ++icl) {
      int ic = pass * 8 + icl;
      float a[3][6];
#pragma unroll
      for (int dy = 0; dy < 3; ++dy)
#pragma unroll
        for (int dx = 0; dx < 6; ++dx)
          a[dy][dx] = s_in[(icl * 18 + r + dy) * 35 + c4 + dx];
      const float* wb = wf + W2 + ic * 9;
#pragma unroll
      for (int o = 0; o < 16; ++o) {
        const float* wo = wb + (ocb + o) * 144;
        float w0 = wo[0], w1 = wo[1], w2 = wo[2], w3 = wo[3], w4 = wo[4],
              w5 = wo[5], w6 = wo[6], w7 = wo[7], w8 = wo[8];
#pragma unroll
        for (int p = 0; p < 4; ++p)
          acc[o][p] += a[0][p] * w0 + a[0][p + 1] * w1 + a[0][p + 2] * w2 +
                       a[1][p] * w3 + a[1][p + 1] * w4 + a[1][p + 2] * w5 +
                       a[2][p] * w6 + a[2][p + 1] * w7 + a[2][p + 2] * w8;
      }
    }
  }
  int opix = ((y0 + r) << 7) + x0 + c4;
#pragma unroll
  for (int o = 0; o < 16; ++o) {
    float b = wf[B2 + ocb + o];
    ushort4 v;
    v.x = f2us(fmaxf(acc[o][0] + b, 0.f));
    v.y = f2us(fmaxf(acc[o][1] + b, 0.f));
    v.z = f2us(fmaxf(acc[o][2] + b, 0.f));
    v.w = f2us(fmaxf(acc[o][3] + b, 0.f));
    *(ushort4*)&out[((long)(n * 32 + ocb + o) << 14) + opix] = v;
  }
}

// ---------- conv3 (big path): 9-tap MFMA implicit GEMM, NHWC ----------
__global__ __launch_bounds__(256) void conv3m_k(const u16* __restrict__ h2t,
                                                const u16* __restrict__ WT3,
                                                const float* __restrict__ wf,
                                                u16* __restrict__ h3t) {
  int bx = blockIdx.x;
  int img = bx >> 6;
  int t = bx & 63;
  int ty0 = (t >> 3) << 4, tx0 = (t & 7) << 4;
  int tid = threadIdx.x;
  int wave = tid >> 6, lane = tid & 63;
  int l15 = lane & 15, lk = lane >> 4;
  long ibase = (long)img << 14;
  short8v B[9];
#pragma unroll
  for (int tap = 0; tap < 9; ++tap)
    B[tap] = *(const short8v*)&WT3[tap * 512 + l15 * 32 + lk * 8];
  float bias = wf[B3 + l15];
#pragma unroll 1
  for (int rg = 0; rg < 4; ++rg) {
    int y = ty0 + wave * 4 + rg;
    f32x4 acc = {};
#pragma unroll
    for (int tap = 0; tap < 9; ++tap) {
      int dy = tap / 3 - 1, dx = tap % 3 - 1;
      int yy = y + dy, xx = tx0 + l15 + dx;
      short8v a = {};
      if (yy >= 0 && yy < 128 && xx >= 0 && xx < 128)
        a = *(const short8v*)&h2t[(ibase + (yy << 7) + xx) * 32 + lk * 8];
      acc = __builtin_amdgcn_mfma_f32_16x16x32_bf16(a, B[tap], acc, 0, 0, 0);
    }
#pragma unroll
    for (int q = 0; q < 4; ++q) {
      int px = tx0 + lk * 4 + q;
      h3t[(ibase + (y << 7) + px) * 16 + l15] = f2us(fmaxf(acc[q] + bias, 0.f));
    }
  }
}

// ---------- conv3 (small path): round-10 VALU version, planar ----------
__global__ __launch_bounds__(256) void conv3_k(const u16* __restrict__ h2c,
                                               const float* __restrict__ wf,
                                               u16* __restrict__ h3c) {
  __shared__ float s_in[8 * 18 * 35];
  int bx = blockIdx.x;
  int n = bx >> 5;
  int rem = bx & 31;
  int y0 = (rem >> 2) << 4;
  int x0 = (rem & 3) << 5;
  int tid = threadIdx.x;
  int r = tid >> 4;
  int c2 = (tid & 15) << 1;
  float acc[16][2];
#pragma unroll
  for (int o = 0; o < 16; ++o) { acc[o][0] = 0.f; acc[o][1] = 0.f; }
#pragma unroll 1
  for (int pass = 0; pass < 4; ++pass) {
    __syncthreads();
    for (int i = tid; i < 4896; i += 256) {
      int icl = i / 612;
      int p = i - icl * 612;
      int py = p / 34, px = p - py * 34;
      int gy = y0 + py - 1, gx = x0 + px - 1;
      float v = 0.f;
      if (gy >= 0 && gy < 128 && gx >= 0 && gx < 128)
        v = us2f(h2c[((long)(n * 32 + pass * 8 + icl) << 14) + (gy << 7) + gx]);
      s_in[(icl * 18 + py) * 35 + px] = v;
    }
    __syncthreads();
#pragma unroll 1
    for (int icl = 0; icl < 8; ++icl) {
      int ic = pass * 8 + icl;
      float a[3][4];
#pragma unroll
      for (int dy = 0; dy < 3; ++dy)
#pragma unroll
        for (int dx = 0; dx < 4; ++dx)
          a[dy][dx] = s_in[(icl * 18 + r + dy) * 35 + c2 + dx];
#pragma unroll
      for (int o = 0; o < 16; ++o) {
        const float* wo = wf + W3 + o * 288 + ic * 9;
        float w0 = wo[0], w1 = wo[1], w2 = wo[2], w3 = wo[3], w4 = wo[4],
              w5 = wo[5], w6 = wo[6], w7 = wo[7], w8 = wo[8];
#pragma unroll
        for (int p = 0; p < 2; ++p)
          acc[o][p] += a[0][p] * w0 + a[0][p + 1] * w1 + a[0][p + 2] * w2 +
                       a[1][p] * w3 + a[1][p + 1] * w4 + a[1][p + 2] * w5 +
                       a[2][p] * w6 + a[2][p + 1] * w7 + a[2][p + 2] * w8;
      }
    }
  }
  int opix = ((y0 + r) << 7) + x0 + c2;
#pragma unroll
  for (int o = 0; o < 16; ++o) {
    float b = wf[B3 + o];
    u32 v = pk2(fmaxf(acc[o][0] + b, 0.f), fmaxf(acc[o][1] + b, 0.f));
    *(u32*)&h3c[((long)(n * 16 + o) << 14) + opix] = v;
  }
}

// ---------- conv4 (big path): NHWC direct, 1 px/thread, no LDS ----------
__global__ __launch_bounds__(256) void conv4n_k(const u16* __restrict__ h3t,
                                                const float* __restrict__ wf,
                                                float* __restrict__ x1f,
                                                void* __restrict__ out0,
                                                const int* __restrict__ flag) {
  int pix = blockIdx.x * 256 + threadIdx.x;
  int loc = pix & 16383;
  int y = loc >> 7, x = loc & 127;
  float acc = wf[B4];
#pragma unroll
  for (int tap = 0; tap < 9; ++tap) {
    int dy = tap / 3 - 1, dx = tap % 3 - 1;
    int yy = y + dy, xx = x + dx;
    if (yy >= 0 && yy < 128 && xx >= 0 && xx < 128) {
      const u16* v = &h3t[((long)pix + (dy << 7) + dx) * 16];
      uint4 a = *(const uint4*)v;
      uint4 b = *(const uint4*)(v + 8);
      u32 vv[8] = {a.x, a.y, a.z, a.w, b.x, b.y, b.z, b.w};
      float s = 0.f;
#pragma unroll
      for (int h = 0; h < 8; ++h) {
        s += us2f((u16)(vv[h] & 0xFFFF)) * wf[W4 + (2 * h) * 9 + tap];
        s += us2f((u16)(vv[h] >> 16)) * wf[W4 + (2 * h + 1) * 9 + tap];
      }
      acc += s;
    }
  }
  x1f[pix] = acc;
  if (*flag) ((u16*)out0)[pix] = f2us(acc);
  else ((float*)out0)[pix] = acc;
}

// ---------- conv4 (small path): planar, LDS version ----------
__global__ __launch_bounds__(256) void conv4_k(const u16* __restrict__ h3c,
                                               const float* __restrict__ wf,
                                               float* __restrict__ x1f,
                                               void* __restrict__ out0,
                                               const int* __restrict__ flag, int img0) {
  __shared__ float s_in[16 * 324];
  int bx = blockIdx.x;
  int n = bx >> 6;
  int ty0 = ((bx >> 3) & 7) << 4, tx0 = (bx & 7) << 4;
  int tid = threadIdx.x;
  for (int i = tid; i < 16 * 324; i += 256) {
    int ic = i / 324, p = i - ic * 324;
    int py = p / 18, px = p - py * 18;
    int gy = ty0 + py - 1, gx = tx0 + px - 1;
    float v = 0.f;
    if (gy >= 0 && gy < 128 && gx >= 0 && gx < 128)
      v = us2f(h3c[((long)(n * 16 + ic) << 14) + (gy << 7) + gx]);
    s_in[i] = v;
  }
  __syncthreads();
  int ty = tid >> 4, tx = tid & 15;
  float acc = wf[B4];
#pragma unroll 1
  for (int ic = 0; ic < 16; ++ic) {
    const float* bi = &s_in[ic * 324 + ty * 18 + tx];
    const float* w = wf + W4 + ic * 9;
    acc += bi[0] * w[0] + bi[1] * w[1] + bi[2] * w[2] + bi[18] * w[3] + bi[19] * w[4] +
           bi[20] * w[5] + bi[36] * w[6] + bi[37] * w[7] + bi[38] * w[8];
  }
  int idx = ((img0 + n) << 14) + ((ty0 + ty) << 7) + (tx0 + tx);
  x1f[idx] = acc;
  if (*flag) ((u16*)out0)[idx] = f2us(acc);
  else ((float*)out0)[idx] = acc;
}

// ---------- graph node features ----------
__global__ void gather_h0_k(const void* __restrict__ pos, const void* __restrict__ xn,
                            const int* __restrict__ batch, const float* __restrict__ x1f,
                            float* __restrict__ h0, const int* __restrict__ flag) {
  int n = blockIdx.x * 256 + threadIdx.x;
  if (n >= NN) return;
  int isbf = *flag;
  float px = ldin(pos, 2 * n, isbf), py = ldin(pos, 2 * n + 1, isbf);
  int ix = (int)rintf((px / 20.0f) * 127.0f);
  int iy = (int)rintf((py / 20.0f) * 127.0f);
  ix = min(max(ix, 0), 127);
  iy = min(max(iy, 0), 127);
  float cn = x1f[(batch[n] << 14) + (iy << 7) + ix];
  float* o = h0 + n * 8;
#pragma unroll
  for (int k = 0; k < 5; ++k) o[k] = ldin(xn, n * 5 + k, isbf);
  o[5] = px;
  o[6] = py;
  o[7] = cn;
}

// ---------- CSR build ----------
__global__ void deg_k(const int* __restrict__ dst, int* __restrict__ deg) {
  int e = blockIdx.x * 256 + threadIdx.x;
  if (e < NE) atomicAdd(&deg[dst[e]], 1);
}
__global__ void scanA_k(const int* __restrict__ deg, int* __restrict__ bsum) {
  __shared__ int s[256];
  int i = blockIdx.x * 256 + threadIdx.x;
  s[threadIdx.x] = (i < NN) ? deg[i] : 0;
  __syncthreads();
  for (int o = 128; o; o >>= 1) {
    if (threadIdx.x < o) s[threadIdx.x] += s[threadIdx.x + o];
    __syncthreads();
  }
  if (threadIdx.x == 0) bsum[blockIdx.x] = s[0];
}
__global__ __launch_bounds__(512) void scanB_k(const int* __restrict__ bsum,
                                               int* __restrict__ bpre) {
  __shared__ int s[512];
  int t = threadIdx.x;
  int v = (t < NBLK) ? bsum[t] : 0;
  s[t] = v;
  __syncthreads();
  for (int o = 1; o < 512; o <<= 1) {
    int u = (t >= o) ? s[t - o] : 0;
    __syncthreads();
    s[t] += u;
    __syncthreads();
  }
  if (t < NBLK) bpre[t] = s[t] - v;
}
__global__ void scanC_k(const int* __restrict__ deg, const int* __restrict__ bpre,
                        int* __restrict__ off, int* __restrict__ curs,
                        float* __restrict__ invd) {
  __shared__ int s[256];
  int i = blockIdx.x * 256 + threadIdx.x, t = threadIdx.x;
  int v = (i < NN) ? deg[i] : 0;
  s[t] = v;
  __syncthreads();
  for (int o = 1; o < 256; o <<= 1) {
    int u = (t >= o) ? s[t - o] : 0;
    __syncthreads();
    s[t] += u;
    __syncthreads();
  }
  if (i < NN) {
    int e = bpre[blockIdx.x] + s[t] - v;
    off[i] = e;
    curs[i] = e;
    invd[i] = 1.0f / fmaxf((float)v, 1.0f);
  }
  if (i == 0) off[NN] = NE;
}
__global__ void fill_k(const int* __restrict__ src, const int* __restrict__ dst,
                       int* __restrict__ curs, int* __restrict__ ss) {
  int e = blockIdx.x * 256 + threadIdx.x;
  if (e < NE) ss[atomicAdd(&curs[dst[e]], 1)] = src[e];
}

// ---------- SAGE layer 0 ----------
__global__ void agg8_k(const float* __restrict__ h0, const int* __restrict__ off,
                       const int* __restrict__ ss, const float* __restrict__ invd,
                       float* __restrict__ m8) {
  int gid = blockIdx.x * 256 + threadIdx.x;
  if (gid >= NN * 8) return;
  int n = gid >> 3, f = gid & 7;
  int e0 = off[n], e1 = off[n + 1];
  float s = 0.f;
  for (int j = e0; j < e1; ++j) s += h0[ss[j] * 8 + f];
  m8[gid] = s * invd[n];
}
__global__ void combine0_k(const float* __restrict__ h0, const float* __restrict__ m8,
                           const float* __restrict__ wl, const float* __restrict__ wr,
                           const float* __restrict__ bs, u16* __restrict__ OUT) {
  int gid = blockIdx.x * 256 + threadIdx.x;
  int n = gid >> 7, fo = gid & 127;
  float acc = bs[fo];
#pragma unroll
  for (int fi = 0; fi < 8; ++fi)
    acc += m8[n * 8 + fi] * wl[fi * 128 + fo] + h0[n * 8 + fi] * wr[fi * 128 + fo];
  OUT[gid] = f2us(fmaxf(acc, 0.f));
}

// ---------- SAGE 128->128: 16 nodes/block, 512 thr (1 node per 32-lane group) ----------
__global__ __launch_bounds__(512) void sage_mfma_k(
    const u16* __restrict__ X, const int* __restrict__ off, const int* __restrict__ ss,
    const float* __restrict__ invd, const u16* __restrict__ WT,
    const float* __restrict__ bs, u16* __restrict__ OUT) {
  __shared__ __align__(16) u16 sM[16 * 128];  // 4 KB
  int tid = threadIdx.x;
  int nodeBase = blockIdx.x * 16;  // 6250 * 16 = NN exactly
  {
    int grp = tid >> 5, t = tid & 31;   // 16 groups x 1 node
    int elane = t >> 3;  // 0..3 edge lanes
    int fg = t & 7;      // 8 f-lanes x 16 features
    int nl = grp;
    int node = nodeBase + nl;
    int e0 = off[node], e1 = off[node + 1];
    int j0 = e0 + elane;
    int sidx = (j0 < e1) ? ss[j0] : -1;
    float s[16];
#pragma unroll
    for (int k = 0; k < 16; ++k) s[k] = 0.f;
    if (sidx >= 0) {
      const u16* row = &X[(long)sidx * 128 + fg * 16];
      ushort4 r0 = *(const ushort4*)row;
      ushort4 r1 = *(const ushort4*)(row + 4);
      ushort4 r2 = *(const ushort4*)(row + 8);
      ushort4 r3 = *(const ushort4*)(row + 12);
      s[0] += us2f(r0.x);  s[1] += us2f(r0.y);  s[2] += us2f(r0.z);  s[3] += us2f(r0.w);
      s[4] += us2f(r1.x);  s[5] += us2f(r1.y);  s[6] += us2f(r1.z);  s[7] += us2f(r1.w);
      s[8] += us2f(r2.x);  s[9] += us2f(r2.y);  s[10] += us2f(r2.z); s[11] += us2f(r2.w);
      s[12] += us2f(r3.x); s[13] += us2f(r3.y); s[14] += us2f(r3.z); s[15] += us2f(r3.w);
    }
    for (int j = j0 + 4; j < e1; j += 4) {
      const u16* row = &X[(long)ss[j] * 128 + fg * 16];
      ushort4 r0 = *(const ushort4*)row;
      ushort4 r1 = *(const ushort4*)(row + 4);
      ushort4 r2 = *(const ushort4*)(row + 8);
      ushort4 r3 = *(const ushort4*)(row + 12);
      s[0] += us2f(r0.x);  s[1] += us2f(r0.y);  s[2] += us2f(r0.z);  s[3] += us2f(r0.w);
      s[4] += us2f(r1.x);  s[5] += us2f(r1.y);  s[6] += us2f(r1.z);  s[7] += us2f(r1.w);
      s[8] += us2f(r2.x);  s[9] += us2f(r2.y);  s[10] += us2f(r2.z); s[11] += us2f(r2.w);
      s[12] += us2f(r3.x); s[13] += us2f(r3.y); s[14] += us2f(r3.z); s[15] += us2f(r3.w);
    }
#pragma unroll
    for (int k = 0; k < 16; ++k) {
      s[k] += __shfl_xor(s[k], 8);
      s[k] += __shfl_xor(s[k], 16);
    }
    if (elane == 0) {
      float iv = invd[node];
      uint4 w0, w1;
      w0.x = pk2(s[0] * iv, s[1] * iv);   w0.y = pk2(s[2] * iv, s[3] * iv);
      w0.z = pk2(s[4] * iv, s[5] * iv);   w0.w = pk2(s[6] * iv, s[7] * iv);
      w1.x = pk2(s[8] * iv, s[9] * iv);   w1.y = pk2(s[10] * iv, s[11] * iv);
      w1.z = pk2(s[12] * iv, s[13] * iv); w1.w = pk2(s[14] * iv, s[15] * iv);
      int f0 = fg * 16;
      int swz = (nl & 7) << 3;
      *(uint4*)&sM[nl * 128 + (f0 ^ swz)] = w0;
      *(uint4*)&sM[nl * 128 + ((f0 + 8) ^ swz)] = w1;
    }
  }
  __syncthreads();
  if (tid >= 64) return;  // phase 2: wave 0 handles all 16 nodes
  int lane = tid;
  int l15 = lane & 15, lk = lane >> 4;
  int arow = nodeBase + l15;
  int mrow = l15;
  f32x4 acc[8] = {};
#pragma unroll 1
  for (int ks = 0; ks < 8; ++ks) {
    short8v a;
    if (ks < 4) {
      a = *(const short8v*)&X[arow * 128 + ks * 32 + lk * 8];
    } else {
      int koff = (ks - 4) * 32 + lk * 8;
      a = *(const short8v*)&sM[mrow * 128 + (koff ^ ((mrow & 7) << 3))];
    }
#pragma unroll
    for (int r = 0; r < 8; ++r) {
      short8v b = *(const short8v*)&WT[(r * 16 + l15) * 256 + ks * 32 + lk * 8];
      acc[r] = __builtin_amdgcn_mfma_f32_16x16x32_bf16(a, b, acc[r], 0, 0, 0);
    }
  }
#pragma unroll
  for (int r = 0; r < 8; ++r) {
    int n = r * 16 + l15;
    float bias = bs[n];
#pragma unroll
    for (int q = 0; q < 4; ++q) {
      int node = nodeBase + lk * 4 + q;
      OUT[node * 128 + n] = f2us(fmaxf(acc[r][q] + bias, 0.f));
    }
  }
}

// ---------- last layer ----------
__global__ __launch_bounds__(256) void dots_k(const u16* __restrict__ X,
                                              const float* __restrict__ wl,
                                              const float* __restrict__ wr,
                                              float* __restrict__ YL,
                                              float* __restrict__ YR) {
  __shared__ float swl[128], swr[128];
  int tid = threadIdx.x;
  if (tid < 128) swl[tid] = wl[tid];
  else swr[tid - 128] = wr[tid - 128];
  __syncthreads();
  int g = blockIdx.x * 8 + (tid >> 5);
  int t = tid & 31, f0 = t * 4;
  if (g >= NN) return;
  ushort4 r = *(const ushort4*)&X[g * 128 + f0];
  float x0 = us2f(r.x), x1 = us2f(r.y), x2 = us2f(r.z), x3 = us2f(r.w);
  float pl = x0 * swl[f0] + x1 * swl[f0 + 1] + x2 * swl[f0 + 2] + x3 * swl[f0 + 3];
  float pr = x0 * swr[f0] + x1 * swr[f0 + 1] + x2 * swr[f0 + 2] + x3 * swr[f0 + 3];
#pragma unroll
  for (int o = 16; o; o >>= 1) {
    pl += __shfl_xor(pl, o);
    pr += __shfl_xor(pr, o);
  }
  if (t == 0) {
    YL[g] = pl;
    YR[g] = pr;
  }
}

__global__ void last_k(const float* __restrict__ YL, const float* __restrict__ YR,
                       const int* __restrict__ off, const int* __restrict__ ss,
                       const float* __restrict__ invd, const float* __restrict__ bs,
                       void* __restrict__ gout, const int* __restrict__ flag) {
  int n = blockIdx.x * 256 + threadIdx.x;
  if (n >= NN) return;
  int e0 = off[n], e1 = off[n + 1];
  float s0 = 0.f, s1 = 0.f;
  int j = e0;
  for (; j + 1 < e1; j += 2) {
    s0 += YL[ss[j]];
    s1 += YL[ss[j + 1]];
  }
  if (j < e1) s0 += YL[ss[j]];
  float v = YR[n] + (s0 + s1) * invd[n] + bs[0];
  if (*flag) ((u16*)gout)[1048576 + n] = f2us(v);
  else ((float*)gout)[1048576 + n] = v;
}

// ---------- diagnostic ----------
__global__ void diag_k(u16* out, int n, u16 v) {
  int i = blockIdx.x * 256 + threadIdx.x;
  if (i < n) out[i] = v;
}

extern "C" void kernel_launch(void* const* d_in, const int* in_sizes, int n_in,
                              void* d_out, int out_size, void* d_ws, size_t ws_size,
                              hipStream_t stream) {
  const void* x128 = d_in[0];
  const void* xn = d_in[1];
  const void* pos = d_in[2];
  const int* eidx = (const int*)d_in[3];
  const int* batch = (const int*)d_in[4];
  const int* esrc = eidx;
  const int* edst = eidx + NE;

  const size_t REQUIRED = 66910000;
  const size_t REQUIRED_BIG = 210640000;
  if (ws_size < REQUIRED) {
    union { float f; u32 i; } c;
    c.f = (float)(ws_size >> 20);
    diag_k<<<(out_size + 255) / 256, 256, 0, stream>>>((u16*)d_out, out_size,
                                                       (u16)(c.i >> 16));
    return;
  }
  const bool big = (ws_size >= REQUIRED_BIG);

  char* ws = (char*)d_ws;
  float* x1f = (float*)ws;                   // dead after gather_h0
  u16* WT1 = (u16*)(ws + 0);                 // OVERLAYS x1f: write only after gather_h0!
  u16* WT2 = (u16*)(ws + 65536);
  float* YL = (float*)(ws + 131072);
  float* YR = (float*)(ws + 531072);
  u16* h1c = (u16*)(ws + 4194304);
  u16* h2c = big ? (u16*)(ws + 71303168) : (u16*)(ws + 20971520);
  u16* h3c = h1c;
  u16* WT3 = (u16*)(ws + 138412032);         // big-path region only
  u16* WT2M = (u16*)(ws + 138421248);
  float* h0 = (float*)(ws + 4194304);
  float* m8 = (float*)(ws + 7394304);
  u16* HA = (u16*)(ws + 10594304);
  u16* HB = (u16*)(ws + 36194304);
  size_t base = big ? 205520896UL : 61794304UL;
  float* wf = (float*)(ws + base);
  int* deg = (int*)(ws + base + 312320);
  float* invd = (float*)(ws + base + 712320);
  int* noff = (int*)(ws + base + 1112320);
  int* curs = (int*)(ws + base + 1512576);
  int* ssrc = (int*)(ws + base + 1912576);
  int* bsum = (int*)(ws + base + 5112576);
  int* bpre = (int*)(ws + base + 5114368);
  int* flag = (int*)(ws + base + 5116160);

  detect_k<<<1, 64, 0, stream>>>(x128, flag);

  Jobs jb;
  const int jin[19] = {6, 7, 8, 9, 10, 11, 12, 13, 14, 15, 16, 17, 18, 19, 20, 21, 22, 23, 24};
  const int joff[19] = {B1, W2, B2, W3, B3, W4, B4, WL0, WR0, BS0, WL1, WR1, BS1,
                        WL2, WR2, BS2, WL3, WR3, BS3};
  const int jn[19] = {16, 4608, 32, 4608, 16, 144, 1, 1024, 1024, 128, 16384, 16384,
                      128, 16384, 16384, 128, 128, 128, 1};
  for (int j = 0; j < 19; ++j) { jb.p[j] = d_in[jin[j]]; jb.off[j] = joff[j]; jb.n[j] = jn[j]; }
  cvt_all_k<<<dim3(64, 19), 256, 0, stream>>>(jb, wf, flag);
  w1eff_k<<<1, 256, 0, stream>>>(d_in[5], wf, flag);

  if (big) {
    wcat3_k<<<18, 256, 0, stream>>>(wf, WT3);
    wcat2m_k<<<20, 256, 0, stream>>>(wf, WT2M);
    conv1_k<true><<<4096, 256, 0, stream>>>(x128, wf, h1c, flag, 0);
    conv2m_k<<<4096, 256, 0, stream>>>(h1c, WT2M, wf, h2c);
    conv3m_k<<<4096, 256, 0, stream>>>(h2c, WT3, wf, h3c);
    conv4n_k<<<4096, 256, 0, stream>>>(h3c, wf, x1f, d_out, flag);
  } else {
    for (int c = 0; c < 4; ++c) {
      int img0 = c * 16;
      conv1_k<false><<<1024, 256, 0, stream>>>(x128, wf, h1c, flag, img0);
      conv2_k<<<512, 256, 0, stream>>>(h1c, wf, h2c);
      conv3_k<<<512, 256, 0, stream>>>(h2c, wf, h3c);
      conv4_k<<<1024, 256, 0, stream>>>(h3c, wf, x1f, d_out, flag, img0);
    }
  }

  gather_h0_k<<<(NN + 255) / 256, 256, 0, stream>>>(pos, xn, batch, x1f, h0, flag);
  // x1f now dead -> safe to build WT1/WT2 in its region
  wcat_k<<<128, 256, 0, stream>>>(wf, WT1, WT2);

  hipMemsetAsync(deg, 0, NN * sizeof(int), stream);
  deg_k<<<(NE + 255) / 256, 256, 0, stream>>>(edst, deg);
  scanA_k<<<NBLK, 256, 0, stream>>>(deg, bsum);
  scanB_k<<<1, 512, 0, stream>>>(bsum, bpre);
  scanC_k<<<NBLK, 256, 0, stream>>>(deg, bpre, noff, curs, invd);
  fill_k<<<(NE + 255) / 256, 256, 0, stream>>>(esrc, edst, curs, ssrc);

  agg8_k<<<(NN * 8 + 255) / 256, 256, 0, stream>>>(h0, noff, ssrc, invd, m8);
  combine0_k<<<NN * 128 / 256, 256, 0, stream>>>(h0, m8, wf + WL0, wf + WR0, wf + BS0, HA);
  sage_mfma_k<<<6250, 512, 0, stream>>>(HA, noff, ssrc, invd, WT1, wf + BS1, HB);
  sage_mfma_k<<<6250, 512, 0, stream>>>(HB, noff, ssrc, invd, WT2, wf + BS2, HA);
  dots_k<<<12500, 256, 0, stream>>>(HA, wf + WL3, wf + WR3, YL, YR);
  last_k<<<(NN + 255) / 256, 256, 0, stream>>>(YL, YR, noff, ssrc, invd, wf + BS3,
                                               d_out, flag);
}